// Round 13
// baseline (80.760 us; speedup 1.0000x reference)
//
#include <hip/hip_runtime.h>

#define D 64
#define H 256
#define SRC_MASK ((1u << 23) - 1)

// ---- tier-1 (fixed-capacity) params ----
#define NBF 512             // buckets
#define NPBF 256            // max nodes per bucket
#define CAPF 4096           // packed slots per bucket
#define PJ 8                // partition: edges per thread

// ---- tier-2 (round-8 proven path) params ----
#define NB2 512
#define NPB2 256
#define CAP2 6144
#define PEPT 16

typedef __bf16 bf16x8 __attribute__((ext_vector_type(8)));
typedef float f32x16 __attribute__((ext_vector_type(16)));
typedef unsigned int uint4v __attribute__((ext_vector_type(4)));

__device__ inline unsigned pack_bf16x2(float a, float b) {
    unsigned short ua = __builtin_bit_cast(unsigned short, (__bf16)a);
    unsigned short ub = __builtin_bit_cast(unsigned short, (__bf16)b);
    return (unsigned)ua | ((unsigned)ub << 16);
}

__device__ inline void lane32_swap(unsigned x, unsigned y, unsigned& o0, unsigned& o1) {
#if __has_builtin(__builtin_amdgcn_permlane32_swap)
    typedef unsigned int uint2v __attribute__((ext_vector_type(2)));
    uint2v r = __builtin_amdgcn_permlane32_swap(x, y, false, false);
    o0 = r.x; o1 = r.y;
#else
    unsigned xs = __shfl_xor((int)x, 32, 64);
    unsigned ys = __shfl_xor((int)y, 32, 64);
    bool hi = (threadIdx.x & 32) != 0;
    o0 = hi ? ys : x;
    o1 = hi ? y : xs;
#endif
}

// ===========================================================================
// Device helper: compute one weight fragment
// ===========================================================================
__device__ inline bf16x8 weight_frag(const float* __restrict__ W1,
                                     const float* __restrict__ W2,
                                     int fid, int lane) {
    int g = lane >> 5, c = lane & 31;
    bf16x8 v;
    if (fid < 32) {
        int ht = fid >> 2, ks = fid & 3;
        const float* col = W1 + (32 * ht + c);
        int k0 = 16 * ks + 8 * g;
#pragma unroll
        for (int j = 0; j < 8; ++j) v[j] = (__bf16)col[(size_t)(k0 + j) * H];
    } else {
        int f = fid - 32;
        int dt = f >> 4, ks = f & 15;
        const float* col = W2 + (32 * dt + c);
        int k0 = 16 * ks + 8 * g;
#pragma unroll
        for (int j = 0; j < 8; ++j) v[j] = (__bf16)col[(size_t)(k0 + j) * D];
    }
    return v;
}

// ===========================================================================
// TIER 1 — K-A) fused front-end: partition | weight prep | cvt
// ===========================================================================
__global__ __launch_bounds__(1024) void fused_front_kernel(
        const float* __restrict__ feat, unsigned short* __restrict__ featb,
        int n8v,
        const float* __restrict__ W1, const float* __restrict__ W2,
        bf16x8* __restrict__ wf,
        const int* __restrict__ src, const int* __restrict__ dst,
        int* __restrict__ cur,           // [NBF] cursors, [NBF] = ovf count
        unsigned* __restrict__ packed, uint2* __restrict__ ovf,
        int E, int npb, int pB, int prepB) {
    int blk = blockIdx.x;
    int tid = threadIdx.x;

    if (blk >= pB + prepB) {
        int i = (blk - pB - prepB) * 1024 + tid;
        if (i < n8v) {
            const float4* f4 = reinterpret_cast<const float4*>(feat);
            float4 a = f4[2 * i];
            float4 b = f4[2 * i + 1];
            uint4v o = { pack_bf16x2(a.x, a.y), pack_bf16x2(a.z, a.w),
                         pack_bf16x2(b.x, b.y), pack_bf16x2(b.z, b.w) };
            reinterpret_cast<uint4v*>(featb)[i] = o;
        }
        return;
    }
    if (blk >= pB) {
        int fid = (blk - pB) * 16 + (tid >> 6);
        int lane = tid & 63;
        if (fid < 64) wf[fid * 64 + lane] = weight_frag(W1, W2, fid, lane);
        return;
    }

    // ---- partition: one round of PJ edges/thread ----
    __shared__ int cnt[NBF];
    __shared__ int resv[NBF];
    if (tid < NBF) cnt[tid] = 0;
    __syncthreads();
    int e0 = blk * (1024 * PJ);
    unsigned myP[PJ];
    int myB[PJ], myR[PJ];
#pragma unroll
    for (int j = 0; j < PJ; ++j) {
        int e = e0 + j * 1024 + tid;
        if (e < E) {
            int d = dst[e];
            int s = src[e];
            int b = (int)((unsigned)d / (unsigned)npb);
            myB[j] = b;
            myR[j] = atomicAdd(&cnt[b], 1);
            myP[j] = ((unsigned)(d - b * npb) << 23) | (unsigned)s;
        } else {
            myB[j] = -1;
        }
    }
    __syncthreads();
    if (tid < NBF && cnt[tid] > 0)
        resv[tid] = atomicAdd(&cur[tid], cnt[tid]);
    __syncthreads();
#pragma unroll
    for (int j = 0; j < PJ; ++j) {
        if (myB[j] < 0) continue;
        int slot = resv[myB[j]] + myR[j];
        if (slot < CAPF) {
            packed[(size_t)myB[j] * CAPF + slot] = myP[j];
        } else {
            int oi = atomicAdd(&cur[NBF], 1);
            ovf[oi] = make_uint2(((unsigned)myB[j] << 16) | (myP[j] >> 23),
                                 myP[j] & SRC_MASK);
        }
    }
}

// ===========================================================================
// TIER 1 — K-B) FUSED per-bucket sort + gather + MFMA MLP.
// Gather writes rst rows to an XOR-swizzled LDS tile; then the block stages
// the 64 KiB weight fragments in LDS and waves 0..tiles-1 run the MLP on
// their 32-node tile, writing f32 out directly (no rstb round trip).
// LDS ~132 KiB -> 1 block/CU (16 waves).
// ===========================================================================
__global__ __launch_bounds__(1024, 4) void csr_gather_mlp_kernel(
        const unsigned* __restrict__ packed, const int* __restrict__ cur,
        const uint2* __restrict__ ovf,
        const unsigned short* __restrict__ featb,
        const bf16x8* __restrict__ wf,
        const float* __restrict__ b1, const float* __restrict__ b2,
        float* __restrict__ out, int n, int npb) {
    __shared__ int hist[NPBF];
    __shared__ int start[NPBF];
    __shared__ int cursor[NPBF];
    __shared__ unsigned raw[CAPF];     // 16 KiB
    __shared__ int srt[CAPF];          // 16 KiB
    __shared__ bf16x8 rstl[NPBF * 8];  // 32 KiB, slot = ln*8 + (g ^ (ln&7))
    __shared__ bf16x8 swf[64 * 64];    // 64 KiB
    __shared__ float sb1[H];
    __shared__ float sb2[D];

    int b = blockIdx.x;
    int tid = threadIdx.x;
    int node0 = b * npb;

    if (tid < NPBF) hist[tid] = 0;
    __syncthreads();

    int stored = cur[b];
    if (stored > CAPF) stored = CAPF;
    int ovfn = cur[NBF];
    const unsigned* win = packed + (size_t)b * CAPF;

    // pass A: window -> LDS raw + per-node histogram (NT: read-once stream)
    for (int k = tid; k < stored; k += 1024) {
        unsigned p = __builtin_nontemporal_load(win + k);
        raw[k] = p;
        atomicAdd(&hist[p >> 23], 1);
    }
    __syncthreads();

    // 256-entry scan
    if (tid < NPBF) start[tid] = hist[tid];
    __syncthreads();
    for (int o = 1; o < NPBF; o <<= 1) {
        int t = (tid < NPBF && tid >= o) ? start[tid - o] : 0;
        __syncthreads();
        if (tid < NPBF) start[tid] += t;
        __syncthreads();
    }
    if (tid < NPBF) {
        int ex = start[tid] - hist[tid];
        start[tid] = ex;
        cursor[tid] = ex;
    }
    __syncthreads();

    // pass B: ranked LDS->LDS scatter
    for (int k = tid; k < stored; k += 1024) {
        unsigned p = raw[k];
        int pos = atomicAdd(&cursor[p >> 23], 1);
        srt[pos] = (int)(p & SRC_MASK);
    }
    __syncthreads();

    // gather: 8 lanes per node, f32 accumulate, bf16 store into swizzled LDS
    {
        int g = tid & 7;
        const bf16x8* f8 = reinterpret_cast<const bf16x8*>(featb);
        for (int ln = tid >> 3; ln < npb; ln += 128) {
            int node = node0 + ln;
            int slot = ln * 8 + (g ^ (ln & 7));
            if (node >= n) {
                bf16x8 z = {};
                rstl[slot] = z;
                continue;
            }
            bf16x8 self = f8[node * 8 + g];
            float acc[8];
#pragma unroll
            for (int j = 0; j < 8; ++j) acc[j] = (float)self[j];

            int s0 = start[ln];
            int e1 = s0 + hist[ln];
            int i = s0;
            for (; i + 4 <= e1; i += 4) {
                int u0 = srt[i + 0];
                int u1 = srt[i + 1];
                int u2 = srt[i + 2];
                int u3 = srt[i + 3];
                bf16x8 v0 = f8[u0 * 8 + g];
                bf16x8 v1 = f8[u1 * 8 + g];
                bf16x8 v2 = f8[u2 * 8 + g];
                bf16x8 v3 = f8[u3 * 8 + g];
#pragma unroll
                for (int j = 0; j < 8; ++j)
                    acc[j] += ((float)v0[j] + (float)v1[j]) +
                              ((float)v2[j] + (float)v3[j]);
            }
            for (; i < e1; ++i) {
                bf16x8 v = f8[srt[i] * 8 + g];
#pragma unroll
                for (int j = 0; j < 8; ++j) acc[j] += (float)v[j];
            }
            if (ovfn > 0) {   // rare-path correctness: scan spilled edges
                unsigned key = ((unsigned)b << 16) | (unsigned)ln;
                for (int k = 0; k < ovfn; ++k) {
                    uint2 oe = ovf[k];
                    if (oe.x == key) {
                        bf16x8 v = f8[oe.y * 8 + g];
#pragma unroll
                        for (int j = 0; j < 8; ++j) acc[j] += (float)v[j];
                    }
                }
            }

            uint4v o = { pack_bf16x2(acc[0], acc[1]), pack_bf16x2(acc[2], acc[3]),
                         pack_bf16x2(acc[4], acc[5]), pack_bf16x2(acc[6], acc[7]) };
            rstl[slot] = __builtin_bit_cast(bf16x8, o);
        }
    }
    __syncthreads();

    // stage weights + biases
    for (int i = tid; i < 64 * 64; i += 1024) swf[i] = wf[i];
    if (tid < H) sb1[tid] = b1[tid];
    if (tid < D) sb2[tid] = b2[tid];
    __syncthreads();

    // MLP: wave w handles nodes [32w, 32w+32) of this bucket
    int lane = tid & 63;
    int w = tid >> 6;
    int tiles = (npb + 31) >> 5;
    if (w >= tiles) return;
    int c = lane & 31, g2 = lane >> 5;
    int r = 32 * w + c;
    int node = node0 + r;
    bool valid = (r < npb) && (node < n);

    bf16x8 bfr[4];
#pragma unroll
    for (int ks = 0; ks < 4; ++ks)
        bfr[ks] = rstl[r * 8 + ((2 * ks + g2) ^ (r & 7))];

    f32x16 acc2_0 = {};
    f32x16 acc2_1 = {};

#pragma unroll
    for (int ht = 0; ht < 8; ++ht) {
        f32x16 a1 = {};
#pragma unroll
        for (int ks = 0; ks < 4; ++ks)
            a1 = __builtin_amdgcn_mfma_f32_32x32x16_bf16(
                     swf[(ht * 4 + ks) * 64 + lane], bfr[ks], a1, 0, 0, 0);

        float hv[16];
#pragma unroll
        for (int q = 0; q < 4; ++q) {
            float4 bq = *reinterpret_cast<const float4*>(&sb1[32 * ht + 8 * q + 4 * g2]);
            hv[4 * q + 0] = fmaxf(a1[4 * q + 0] + bq.x, 0.0f);
            hv[4 * q + 1] = fmaxf(a1[4 * q + 1] + bq.y, 0.0f);
            hv[4 * q + 2] = fmaxf(a1[4 * q + 2] + bq.z, 0.0f);
            hv[4 * q + 3] = fmaxf(a1[4 * q + 3] + bq.w, 0.0f);
        }

#pragma unroll
        for (int half = 0; half < 2; ++half) {
            const float* hs = hv + 8 * half;
            unsigned plo0 = pack_bf16x2(hs[0], hs[1]);
            unsigned plo1 = pack_bf16x2(hs[2], hs[3]);
            unsigned phi0 = pack_bf16x2(hs[4], hs[5]);
            unsigned phi1 = pack_bf16x2(hs[6], hs[7]);
            unsigned f0, f2, f1, f3;
            lane32_swap(plo0, phi0, f0, f2);
            lane32_swap(plo1, phi1, f1, f3);
            uint4v fr = { f0, f1, f2, f3 };
            bf16x8 b2f = __builtin_bit_cast(bf16x8, fr);
            int ks2 = 2 * ht + half;
            acc2_0 = __builtin_amdgcn_mfma_f32_32x32x16_bf16(
                         swf[(32 + 0 * 16 + ks2) * 64 + lane], b2f, acc2_0, 0, 0, 0);
            acc2_1 = __builtin_amdgcn_mfma_f32_32x32x16_bf16(
                         swf[(32 + 1 * 16 + ks2) * 64 + lane], b2f, acc2_1, 0, 0, 0);
        }
    }

    if (!valid) return;
    float* orow = out + (size_t)node * D;
#pragma unroll
    for (int dt = 0; dt < 2; ++dt) {
        const f32x16& a = dt ? acc2_1 : acc2_0;
#pragma unroll
        for (int q = 0; q < 4; ++q) {
            int d0 = 32 * dt + 8 * q + 4 * g2;
            float4 bq = *reinterpret_cast<const float4*>(&sb2[d0]);
            float4 v;
            v.x = a[4 * q + 0] + bq.x;
            v.y = a[4 * q + 1] + bq.y;
            v.z = a[4 * q + 2] + bq.z;
            v.w = a[4 * q + 3] + bq.w;
            *reinterpret_cast<float4*>(orow + d0) = v;
        }
    }
}

// ===========================================================================
// TIER 2 — round-8 proven path (used when ws too small for tier 1)
// ===========================================================================
__global__ void prep_weights_kernel(const float* __restrict__ W1,
                                    const float* __restrict__ W2,
                                    bf16x8* __restrict__ wf,
                                    int* __restrict__ gz) {
    if (blockIdx.x >= 64) {
        for (int i = threadIdx.x; i < 2 * NB2; i += 64) gz[i] = 0;
        return;
    }
    wf[blockIdx.x * 64 + threadIdx.x] =
        weight_frag(W1, W2, blockIdx.x, threadIdx.x);
}

__global__ __launch_bounds__(256) void cvt_hist_kernel(
        const float* __restrict__ feat, unsigned short* __restrict__ featb,
        int n8, const int* __restrict__ dst, int E, int* __restrict__ gcnt,
        int npb, int nb, int cvtB) {
    int tid = threadIdx.x;
    if ((int)blockIdx.x < cvtB) {
        int i = blockIdx.x * 256 + tid;
        if (i < n8) {
            const float4* f4 = reinterpret_cast<const float4*>(feat);
            float4 a = f4[2 * i];
            float4 b = f4[2 * i + 1];
            uint4v o = { pack_bf16x2(a.x, a.y), pack_bf16x2(a.z, a.w),
                         pack_bf16x2(b.x, b.y), pack_bf16x2(b.z, b.w) };
            reinterpret_cast<uint4v*>(featb)[i] = o;
        }
    } else {
        __shared__ int c[NB2];
        for (int i = tid; i < NB2; i += 256) c[i] = 0;
        __syncthreads();
        int hb = gridDim.x - cvtB;
        for (int e = (blockIdx.x - cvtB) * 256 + tid; e < E; e += hb * 256)
            atomicAdd(&c[(unsigned)dst[e] / (unsigned)npb], 1);
        __syncthreads();
        for (int i = tid; i < nb; i += 256)
            if (c[i] > 0) atomicAdd(&gcnt[i], c[i]);
    }
}

__global__ __launch_bounds__(1024) void partition2_kernel(
        const int* __restrict__ src, const int* __restrict__ dst,
        const int* __restrict__ gcnt, int* __restrict__ cur2,
        unsigned* __restrict__ packed, int E, int npb, int nb) {
    __shared__ int sg[NB2];
    __shared__ int cnt[NB2];
    __shared__ int base_s[NB2];
    int tid = threadIdx.x;
    if (tid < NB2) {
        sg[tid] = (tid < nb) ? gcnt[tid] : 0;
        cnt[tid] = 0;
    }
    __syncthreads();
    for (int o = 1; o < NB2; o <<= 1) {
        int t = (tid < NB2 && tid >= o) ? sg[tid - o] : 0;
        __syncthreads();
        if (tid < NB2) sg[tid] += t;
        __syncthreads();
    }
    int e0 = blockIdx.x * (1024 * PEPT);
    unsigned myP[PEPT];
    int myB[PEPT], myR[PEPT];
#pragma unroll
    for (int j = 0; j < PEPT; ++j) {
        int e = e0 + j * 1024 + tid;
        if (e < E) {
            int d = dst[e];
            int s = src[e];
            int b = (unsigned)d / (unsigned)npb;
            myB[j] = b;
            myR[j] = atomicAdd(&cnt[b], 1);
            myP[j] = ((unsigned)(d - b * npb) << 23) | (unsigned)s;
        } else {
            myB[j] = -1;
        }
    }
    __syncthreads();
    if (tid < nb && cnt[tid] > 0)
        base_s[tid] = (sg[tid] - gcnt[tid]) + atomicAdd(&cur2[tid], cnt[tid]);
    __syncthreads();
#pragma unroll
    for (int j = 0; j < PEPT; ++j) {
        if (myB[j] >= 0) packed[base_s[myB[j]] + myR[j]] = myP[j];
    }
}

__global__ __launch_bounds__(1024, 2) void csr_gather2_kernel(
        const unsigned* __restrict__ packed, const int* __restrict__ gcnt,
        const unsigned short* __restrict__ featb,
        int* __restrict__ csr_g, unsigned short* __restrict__ rstb,
        int n, int npb, int nb) {
    __shared__ int sg[NB2];
    __shared__ int hist[NPB2];
    __shared__ int start[NPB2];
    __shared__ int cursor[NPB2];
    __shared__ unsigned raw[CAP2];
    __shared__ int srt[CAP2];

    int b = blockIdx.x;
    int tid = threadIdx.x;
    int node0 = b * npb;

    if (tid < NB2) sg[tid] = (tid < nb) ? gcnt[tid] : 0;
    if (tid < NPB2) hist[tid] = 0;
    __syncthreads();
    for (int o = 1; o < NB2; o <<= 1) {
        int t = (tid < NB2 && tid >= o) ? sg[tid - o] : 0;
        __syncthreads();
        if (tid < NB2) sg[tid] += t;
        __syncthreads();
    }
    int ie = sg[b];
    int ib = (b > 0) ? sg[b - 1] : 0;
    bool useG = (ie - ib) > CAP2;

    for (int k = ib + tid; k < ie; k += 1024) {
        unsigned p = packed[k];
        if (!useG) raw[k - ib] = p;
        atomicAdd(&hist[p >> 23], 1);
    }
    __syncthreads();

    if (tid < NPB2) start[tid] = hist[tid];
    __syncthreads();
    for (int o = 1; o < NPB2; o <<= 1) {
        int t = (tid < NPB2 && tid >= o) ? start[tid - o] : 0;
        __syncthreads();
        if (tid < NPB2) start[tid] += t;
        __syncthreads();
    }
    if (tid < NPB2) {
        int excl = start[tid] - hist[tid];
        start[tid] = excl;
        cursor[tid] = excl;
    }
    __syncthreads();

    int cnt_e = ie - ib;
    if (!useG) {
        for (int k = tid; k < cnt_e; k += 1024) {
            unsigned p = raw[k];
            int pos = atomicAdd(&cursor[p >> 23], 1);
            srt[pos] = (int)(p & SRC_MASK);
        }
    } else {
        for (int k = ib + tid; k < ie; k += 1024) {
            unsigned p = packed[k];
            int pos = atomicAdd(&cursor[p >> 23], 1);
            csr_g[ib + pos] = (int)(p & SRC_MASK);
        }
    }
    __syncthreads();

    int g = tid & 7;
    const bf16x8* f8 = reinterpret_cast<const bf16x8*>(featb);
    for (int ln = tid >> 3; ln < npb; ln += 128) {
        int node = node0 + ln;
        if (node >= n) break;
        bf16x8 self = f8[node * 8 + g];
        float acc[8];
#pragma unroll
        for (int j = 0; j < 8; ++j) acc[j] = (float)self[j];

        int s0 = start[ln];
        int e1 = s0 + hist[ln];
        const int* lst = useG ? (csr_g + ib) : srt;
        int i = s0;
        for (; i + 4 <= e1; i += 4) {
            int u0 = lst[i + 0];
            int u1 = lst[i + 1];
            int u2 = lst[i + 2];
            int u3 = lst[i + 3];
            bf16x8 v0 = f8[u0 * 8 + g];
            bf16x8 v1 = f8[u1 * 8 + g];
            bf16x8 v2 = f8[u2 * 8 + g];
            bf16x8 v3 = f8[u3 * 8 + g];
#pragma unroll
            for (int j = 0; j < 8; ++j)
                acc[j] += ((float)v0[j] + (float)v1[j]) +
                          ((float)v2[j] + (float)v3[j]);
        }
        for (; i < e1; ++i) {
            bf16x8 v = f8[lst[i] * 8 + g];
#pragma unroll
            for (int j = 0; j < 8; ++j) acc[j] += (float)v[j];
        }

        uint4v o = { pack_bf16x2(acc[0], acc[1]), pack_bf16x2(acc[2], acc[3]),
                     pack_bf16x2(acc[4], acc[5]), pack_bf16x2(acc[6], acc[7]) };
        reinterpret_cast<uint4v*>(rstb)[node * 8 + g] = o;
    }
}

// ===========================================================================
// Standalone MFMA MLP (tier 2/3): out^T = W2^T @ relu(W1^T @ rst^T + b1) + b2
// ===========================================================================
template <bool BF16>
__global__ __launch_bounds__(512, 4) void mlp_mfma_kernel(
        const void* __restrict__ rstv, const bf16x8* __restrict__ wf,
        const float* __restrict__ b1, const float* __restrict__ b2,
        float* __restrict__ out, int n, int ntiles) {
    __shared__ bf16x8 swf[64 * 64];   // 64 KiB
    __shared__ float sb1[H];
    __shared__ float sb2[D];

    for (int i = threadIdx.x; i < 64 * 64; i += 512) swf[i] = wf[i];
    if (threadIdx.x < H) sb1[threadIdx.x] = b1[threadIdx.x];
    if (threadIdx.x < D) sb2[threadIdx.x] = b2[threadIdx.x];
    __syncthreads();

    int lane = threadIdx.x & 63;
    int wid  = threadIdx.x >> 6;
    int g = lane >> 5, c = lane & 31;

    int tile = blockIdx.x * 8 + wid;
    if (tile >= ntiles) return;
    int node = tile * 32 + c;
    bool valid = node < n;
    int nodeC = valid ? node : (n - 1);

    bf16x8 bfr[4];
    if constexpr (BF16) {
        const bf16x8* rb = reinterpret_cast<const bf16x8*>(rstv) +
                           (size_t)nodeC * 8 + g;
#pragma unroll
        for (int ks = 0; ks < 4; ++ks) bfr[ks] = rb[2 * ks];
    } else {
        const float* rrow = reinterpret_cast<const float*>(rstv) +
                            (size_t)nodeC * D + 8 * g;
#pragma unroll
        for (int ks = 0; ks < 4; ++ks) {
            float4 lo = *reinterpret_cast<const float4*>(rrow + 16 * ks);
            float4 hi = *reinterpret_cast<const float4*>(rrow + 16 * ks + 4);
            bf16x8 v;
            v[0] = (__bf16)lo.x; v[1] = (__bf16)lo.y; v[2] = (__bf16)lo.z; v[3] = (__bf16)lo.w;
            v[4] = (__bf16)hi.x; v[5] = (__bf16)hi.y; v[6] = (__bf16)hi.z; v[7] = (__bf16)hi.w;
            bfr[ks] = v;
        }
    }

    f32x16 acc2_0 = {};
    f32x16 acc2_1 = {};

#pragma unroll
    for (int ht = 0; ht < 8; ++ht) {
        f32x16 a1 = {};
#pragma unroll
        for (int ks = 0; ks < 4; ++ks)
            a1 = __builtin_amdgcn_mfma_f32_32x32x16_bf16(
                     swf[(ht * 4 + ks) * 64 + lane], bfr[ks], a1, 0, 0, 0);

        float hv[16];
#pragma unroll
        for (int q = 0; q < 4; ++q) {
            float4 bq = *reinterpret_cast<const float4*>(&sb1[32 * ht + 8 * q + 4 * g]);
            hv[4 * q + 0] = fmaxf(a1[4 * q + 0] + bq.x, 0.0f);
            hv[4 * q + 1] = fmaxf(a1[4 * q + 1] + bq.y, 0.0f);
            hv[4 * q + 2] = fmaxf(a1[4 * q + 2] + bq.z, 0.0f);
            hv[4 * q + 3] = fmaxf(a1[4 * q + 3] + bq.w, 0.0f);
        }

#pragma unroll
        for (int half = 0; half < 2; ++half) {
            const float* hs = hv + 8 * half;
            unsigned plo0 = pack_bf16x2(hs[0], hs[1]);
            unsigned plo1 = pack_bf16x2(hs[2], hs[3]);
            unsigned phi0 = pack_bf16x2(hs[4], hs[5]);
            unsigned phi1 = pack_bf16x2(hs[6], hs[7]);
            unsigned f0, f2, f1, f3;
            lane32_swap(plo0, phi0, f0, f2);
            lane32_swap(plo1, phi1, f1, f3);
            uint4v fr = { f0, f1, f2, f3 };
            bf16x8 b2f = __builtin_bit_cast(bf16x8, fr);
            int ks2 = 2 * ht + half;
            acc2_0 = __builtin_amdgcn_mfma_f32_32x32x16_bf16(
                         swf[(32 + 0 * 16 + ks2) * 64 + lane], b2f, acc2_0, 0, 0, 0);
            acc2_1 = __builtin_amdgcn_mfma_f32_32x32x16_bf16(
                         swf[(32 + 1 * 16 + ks2) * 64 + lane], b2f, acc2_1, 0, 0, 0);
        }
    }

    if (!valid) return;
    float* orow = out + (size_t)node * D;
#pragma unroll
    for (int dt = 0; dt < 2; ++dt) {
        const f32x16& a = dt ? acc2_1 : acc2_0;
#pragma unroll
        for (int q = 0; q < 4; ++q) {
            int d0 = 32 * dt + 8 * q + 4 * g;
            float4 bq = *reinterpret_cast<const float4*>(&sb2[d0]);
            float4 v;
            v.x = a[4 * q + 0] + bq.x;
            v.y = a[4 * q + 1] + bq.y;
            v.z = a[4 * q + 2] + bq.z;
            v.w = a[4 * q + 3] + bq.w;
            *reinterpret_cast<float4*>(orow + d0) = v;
        }
    }
}

// ===========================================================================
// TIER 3 — atomic fallback
// ===========================================================================
__global__ void copy_feat_kernel(const float* __restrict__ feat,
                                 float* __restrict__ rst, int n4) {
    int i = blockIdx.x * blockDim.x + threadIdx.x;
    if (i < n4) {
        reinterpret_cast<float4*>(rst)[i] =
            reinterpret_cast<const float4*>(feat)[i];
    }
}

__global__ void scatter_add_kernel(const float* __restrict__ feat,
                                   const int* __restrict__ src,
                                   const int* __restrict__ dst,
                                   float* rst, int E) {
    int gid = blockIdx.x * blockDim.x + threadIdx.x;
    int e = gid >> 4;
    if (e >= E) return;
    int d4 = (gid & 15) << 2;
    int s = src[e];
    int t = dst[e];
    float4 v = *reinterpret_cast<const float4*>(&feat[s * D + d4]);
    float* p = &rst[t * D + d4];
    atomicAdd(p + 0, v.x);
    atomicAdd(p + 1, v.y);
    atomicAdd(p + 2, v.z);
    atomicAdd(p + 3, v.w);
}

__global__ __launch_bounds__(512) void mlp_valu_kernel(
        const float* rst,
        const float* __restrict__ W1, const float* __restrict__ b1,
        const float* __restrict__ W2, const float* __restrict__ b2,
        float* out, int n) {
    __shared__ float sW1t[H * D];
    __shared__ float sW2 [H * D];
    __shared__ float sb1[H];
    __shared__ float sb2[D];

    for (int i = threadIdx.x; i < D * H; i += 512) {
        int d = i >> 8;
        int j = i & (H - 1);
        sW1t[j * D + d] = W1[i];
        sW2[i] = W2[i];
    }
    if (threadIdx.x < H) sb1[threadIdx.x] = b1[threadIdx.x];
    if (threadIdx.x < D) sb2[threadIdx.x] = b2[threadIdx.x];
    __syncthreads();

    int node = blockIdx.x * 512 + threadIdx.x;
    if (node >= n) return;

    float x[D];
    const float4* xr = reinterpret_cast<const float4*>(&rst[node * D]);
#pragma unroll
    for (int d4 = 0; d4 < D / 4; ++d4) {
        float4 v = xr[d4];
        x[d4 * 4 + 0] = v.x; x[d4 * 4 + 1] = v.y;
        x[d4 * 4 + 2] = v.z; x[d4 * 4 + 3] = v.w;
    }
    float acc[D];
#pragma unroll
    for (int d = 0; d < D; ++d) acc[d] = sb2[d];
    for (int j = 0; j < H; ++j) {
        float h = sb1[j];
        const float4* w1 = reinterpret_cast<const float4*>(&sW1t[j * D]);
#pragma unroll
        for (int d4 = 0; d4 < D / 4; ++d4) {
            float4 w = w1[d4];
            h += x[d4 * 4 + 0] * w.x + x[d4 * 4 + 1] * w.y +
                 x[d4 * 4 + 2] * w.z + x[d4 * 4 + 3] * w.w;
        }
        h = fmaxf(h, 0.0f);
        const float4* w2 = reinterpret_cast<const float4*>(&sW2[j * D]);
#pragma unroll
        for (int d4 = 0; d4 < D / 4; ++d4) {
            float4 w = w2[d4];
            acc[d4 * 4 + 0] += h * w.x; acc[d4 * 4 + 1] += h * w.y;
            acc[d4 * 4 + 2] += h * w.z; acc[d4 * 4 + 3] += h * w.w;
        }
    }
    float4* op = reinterpret_cast<float4*>(&out[node * D]);
#pragma unroll
    for (int d4 = 0; d4 < D / 4; ++d4) {
        float4 v;
        v.x = acc[d4 * 4 + 0]; v.y = acc[d4 * 4 + 1];
        v.z = acc[d4 * 4 + 2]; v.w = acc[d4 * 4 + 3];
        op[d4] = v;
    }
}

// ===========================================================================
extern "C" void kernel_launch(void* const* d_in, const int* in_sizes, int n_in,
                              void* d_out, int out_size, void* d_ws, size_t ws_size,
                              hipStream_t stream) {
    const float* feat = (const float*)d_in[0];
    const float* W1   = (const float*)d_in[1];
    const float* b1   = (const float*)d_in[2];
    const float* W2   = (const float*)d_in[3];
    const float* b2   = (const float*)d_in[4];
    const int*   src  = (const int*)d_in[5];
    const int*   dst  = (const int*)d_in[6];
    float* buf = (float*)d_out;

    int n = in_sizes[0] / D;
    int E = in_sizes[5];
    char* ws = (char*)d_ws;

    // ---------- tier 1 layout ----------
    int npbF = (n + NBF - 1) / NBF;
    int nbF  = (n + npbF - 1) / npbF;
    size_t o1 = 0;
    auto a1 = [&](size_t bytes) { size_t c = o1; o1 = (o1 + bytes + 255) & ~(size_t)255; return c; };
    size_t t1_wf     = a1(64 * 64 * sizeof(bf16x8));
    size_t t1_ctrl   = a1((NBF + 1) * sizeof(int));
    size_t t1_packed = a1((size_t)NBF * CAPF * sizeof(unsigned));
    size_t t1_ovf    = a1((size_t)E * sizeof(uint2));
    size_t t1_featb  = a1((size_t)n * D * 2);
    size_t need1 = o1;
    bool tier1 = (npbF <= NPBF) && (ws_size >= need1);

    if (tier1) {
        bf16x8*   wf     = (bf16x8*)(ws + t1_wf);
        int*      ctrl   = (int*)(ws + t1_ctrl);
        unsigned* packed = (unsigned*)(ws + t1_packed);
        uint2*    ovf    = (uint2*)(ws + t1_ovf);
        unsigned short* featb = (unsigned short*)(ws + t1_featb);

        hipMemsetAsync(ctrl, 0, (NBF + 1) * sizeof(int), stream);

        int n8v  = n * D / 8;
        int cvtB = (n8v + 1023) / 1024;
        int pB   = (E + 1024 * PJ - 1) / (1024 * PJ);
        int prepB = 4;
        fused_front_kernel<<<pB + prepB + cvtB, 1024, 0, stream>>>(
            feat, featb, n8v, W1, W2, wf, src, dst, ctrl, packed, ovf,
            E, npbF, pB, prepB);

        csr_gather_mlp_kernel<<<nbF, 1024, 0, stream>>>(
            packed, ctrl, ovf, featb, wf, b1, b2, buf, n, npbF);
        return;
    }

    // ---------- tier 2 layout (round-8 path) ----------
    int npb2 = (n + NB2 - 1) / NB2;
    int nb2  = (n + npb2 - 1) / npb2;
    size_t o2 = 0;
    auto a2 = [&](size_t bytes) { size_t c = o2; o2 = (o2 + bytes + 255) & ~(size_t)255; return c; };
    size_t t2_wf     = a2(64 * 64 * sizeof(bf16x8));
    size_t t2_gcnt   = a2(2 * NB2 * sizeof(int));
    size_t t2_packed = a2((size_t)E * sizeof(unsigned));
    size_t t2_csrg   = a2((size_t)E * sizeof(int));
    size_t t2_featb  = a2((size_t)n * D * 2);
    size_t t2_rstb   = a2((size_t)n * D * 2);
    size_t need2 = o2;
    bool haveWf = ws_size >= 64 * 64 * sizeof(bf16x8);
    bool tier2  = (npb2 <= NPB2) && (n < (1 << 23)) && (ws_size >= need2);

    if (tier2) {
        bf16x8*   wf     = (bf16x8*)(ws + t2_wf);
        int*      gcnt   = (int*)(ws + t2_gcnt);
        int*      cur2   = gcnt + NB2;
        unsigned* packed = (unsigned*)(ws + t2_packed);
        int*      csr_g  = (int*)(ws + t2_csrg);
        unsigned short* featb = (unsigned short*)(ws + t2_featb);
        unsigned short* rstb  = (unsigned short*)(ws + t2_rstb);

        prep_weights_kernel<<<65, 64, 0, stream>>>(W1, W2, wf, gcnt);

        int n8   = n * D / 8;
        int cvtB = (n8 + 255) / 256;
        cvt_hist_kernel<<<cvtB + 784, 256, 0, stream>>>(
            feat, featb, n8, dst, E, gcnt, npb2, nb2, cvtB);

        int pB2 = (E + 1024 * PEPT - 1) / (1024 * PEPT);
        partition2_kernel<<<pB2, 1024, 0, stream>>>(
            src, dst, gcnt, cur2, packed, E, npb2, nb2);

        csr_gather2_kernel<<<nb2, 1024, 0, stream>>>(
            packed, gcnt, featb, csr_g, rstb, n, npb2, nb2);

        int ntiles = (n + 31) / 32;
        mlp_mfma_kernel<true><<<(ntiles + 7) / 8, 512, 0, stream>>>(
            rstb, wf, b1, b2, buf, n, ntiles);
        return;
    }

    // ---------- tier 3: atomic fallback ----------
    if (haveWf) {
        bf16x8* wf = (bf16x8*)ws;
        prep_weights_kernel<<<64, 64, 0, stream>>>(W1, W2, wf, (int*)ws);
        int n4 = n * D / 4;
        copy_feat_kernel<<<(n4 + 255) / 256, 256, 0, stream>>>(feat, buf, n4);
        int threads = E * 16;
        scatter_add_kernel<<<(threads + 255) / 256, 256, 0, stream>>>(
            feat, src, dst, buf, E);
        int ntiles = (n + 31) / 32;
        mlp_mfma_kernel<false><<<(ntiles + 7) / 8, 512, 0, stream>>>(
            buf, wf, b1, b2, buf, n, ntiles);
    } else {
        int n4 = n * D / 4;
        copy_feat_kernel<<<(n4 + 255) / 256, 256, 0, stream>>>(feat, buf, n4);
        int threads = E * 16;
        scatter_add_kernel<<<(threads + 255) / 256, 256, 0, stream>>>(
            feat, src, dst, buf, E);
        mlp_valu_kernel<<<(n + 511) / 512, 512, 0, stream>>>(
            buf, W1, b1, W2, b2, buf, n);
    }
}

// Round 14
// 79.960 us; speedup vs baseline: 1.0100x; 1.0100x over previous
//
#include <hip/hip_runtime.h>

#define D 64
#define H 256
#define SRC_MASK ((1u << 23) - 1)

// ---- tier-1 (fixed-capacity) params ----
#define NBF 512             // buckets
#define NPBF 256            // max nodes per bucket
#define CAPF 4096           // packed slots per bucket
#define PJ 8                // partition: edges per thread

// ---- tier-2 (round-8 proven path) params ----
#define NB2 512
#define NPB2 256
#define CAP2 6144
#define PEPT 16

typedef __bf16 bf16x8 __attribute__((ext_vector_type(8)));
typedef float f32x16 __attribute__((ext_vector_type(16)));
typedef unsigned int uint4v __attribute__((ext_vector_type(4)));

__device__ inline unsigned pack_bf16x2(float a, float b) {
    unsigned short ua = __builtin_bit_cast(unsigned short, (__bf16)a);
    unsigned short ub = __builtin_bit_cast(unsigned short, (__bf16)b);
    return (unsigned)ua | ((unsigned)ub << 16);
}

__device__ inline void lane32_swap(unsigned x, unsigned y, unsigned& o0, unsigned& o1) {
#if __has_builtin(__builtin_amdgcn_permlane32_swap)
    typedef unsigned int uint2v __attribute__((ext_vector_type(2)));
    uint2v r = __builtin_amdgcn_permlane32_swap(x, y, false, false);
    o0 = r.x; o1 = r.y;
#else
    unsigned xs = __shfl_xor((int)x, 32, 64);
    unsigned ys = __shfl_xor((int)y, 32, 64);
    bool hi = (threadIdx.x & 32) != 0;
    o0 = hi ? ys : x;
    o1 = hi ? y : xs;
#endif
}

// ===========================================================================
// Device helper: compute one weight fragment
// ===========================================================================
__device__ inline bf16x8 weight_frag(const float* __restrict__ W1,
                                     const float* __restrict__ W2,
                                     int fid, int lane) {
    int g = lane >> 5, c = lane & 31;
    bf16x8 v;
    if (fid < 32) {
        int ht = fid >> 2, ks = fid & 3;
        const float* col = W1 + (32 * ht + c);
        int k0 = 16 * ks + 8 * g;
#pragma unroll
        for (int j = 0; j < 8; ++j) v[j] = (__bf16)col[(size_t)(k0 + j) * H];
    } else {
        int f = fid - 32;
        int dt = f >> 4, ks = f & 15;
        const float* col = W2 + (32 * dt + c);
        int k0 = 16 * ks + 8 * g;
#pragma unroll
        for (int j = 0; j < 8; ++j) v[j] = (__bf16)col[(size_t)(k0 + j) * D];
    }
    return v;
}

// ===========================================================================
// TIER 1 — K-A) fused front-end: partition | weight prep | cvt
// ===========================================================================
__global__ __launch_bounds__(1024) void fused_front_kernel(
        const float* __restrict__ feat, unsigned short* __restrict__ featb,
        int n8v,
        const float* __restrict__ W1, const float* __restrict__ W2,
        bf16x8* __restrict__ wf,
        const int* __restrict__ src, const int* __restrict__ dst,
        int* __restrict__ cur,           // [NBF] cursors, [NBF] = ovf count
        unsigned* __restrict__ packed, uint2* __restrict__ ovf,
        int E, int npb, int pB, int prepB) {
    int blk = blockIdx.x;
    int tid = threadIdx.x;

    if (blk >= pB + prepB) {
        int i = (blk - pB - prepB) * 1024 + tid;
        if (i < n8v) {
            const float4* f4 = reinterpret_cast<const float4*>(feat);
            float4 a = f4[2 * i];
            float4 b = f4[2 * i + 1];
            uint4v o = { pack_bf16x2(a.x, a.y), pack_bf16x2(a.z, a.w),
                         pack_bf16x2(b.x, b.y), pack_bf16x2(b.z, b.w) };
            reinterpret_cast<uint4v*>(featb)[i] = o;
        }
        return;
    }
    if (blk >= pB) {
        int fid = (blk - pB) * 16 + (tid >> 6);
        int lane = tid & 63;
        if (fid < 64) wf[fid * 64 + lane] = weight_frag(W1, W2, fid, lane);
        return;
    }

    // ---- partition: one round of PJ edges/thread ----
    __shared__ int cnt[NBF];
    __shared__ int resv[NBF];
    if (tid < NBF) cnt[tid] = 0;
    __syncthreads();
    int e0 = blk * (1024 * PJ);
    unsigned myP[PJ];
    int myB[PJ], myR[PJ];
#pragma unroll
    for (int j = 0; j < PJ; ++j) {
        int e = e0 + j * 1024 + tid;
        if (e < E) {
            int d = dst[e];
            int s = src[e];
            int b = (int)((unsigned)d / (unsigned)npb);
            myB[j] = b;
            myR[j] = atomicAdd(&cnt[b], 1);
            myP[j] = ((unsigned)(d - b * npb) << 23) | (unsigned)s;
        } else {
            myB[j] = -1;
        }
    }
    __syncthreads();
    if (tid < NBF && cnt[tid] > 0)
        resv[tid] = atomicAdd(&cur[tid], cnt[tid]);
    __syncthreads();
#pragma unroll
    for (int j = 0; j < PJ; ++j) {
        if (myB[j] < 0) continue;
        int slot = resv[myB[j]] + myR[j];
        if (slot < CAPF) {
            packed[(size_t)myB[j] * CAPF + slot] = myP[j];
        } else {
            int oi = atomicAdd(&cur[NBF], 1);
            ovf[oi] = make_uint2(((unsigned)myB[j] << 16) | (myP[j] >> 23),
                                 myP[j] & SRC_MASK);
        }
    }
}

// ===========================================================================
// TIER 1 — K-B) per-bucket counting sort (LDS) + single-pass gather.
// 8 lanes/node, 16 B bf16x8 loads, 8-deep edge unroll for MLP, f32 acc.
// ===========================================================================
__global__ __launch_bounds__(1024, 2) void csr_gather_fixed_kernel(
        const unsigned* __restrict__ packed, const int* __restrict__ cur,
        const uint2* __restrict__ ovf,
        const unsigned short* __restrict__ featb,
        unsigned short* __restrict__ rstb, int n, int npb) {
    __shared__ int hist[NPBF];
    __shared__ int start[NPBF];
    __shared__ int cursor[NPBF];
    __shared__ unsigned raw[CAPF];
    __shared__ int srt[CAPF];

    int b = blockIdx.x;
    int tid = threadIdx.x;
    int node0 = b * npb;

    if (tid < NPBF) hist[tid] = 0;
    __syncthreads();

    int stored = cur[b];
    if (stored > CAPF) stored = CAPF;
    int ovfn = cur[NBF];
    const unsigned* win = packed + (size_t)b * CAPF;

    // pass A: window -> LDS raw + per-node histogram (NT: read-once stream)
    for (int k = tid; k < stored; k += 1024) {
        unsigned p = __builtin_nontemporal_load(win + k);
        raw[k] = p;
        atomicAdd(&hist[p >> 23], 1);
    }
    __syncthreads();

    // 256-entry scan
    if (tid < NPBF) start[tid] = hist[tid];
    __syncthreads();
    for (int o = 1; o < NPBF; o <<= 1) {
        int t = (tid < NPBF && tid >= o) ? start[tid - o] : 0;
        __syncthreads();
        if (tid < NPBF) start[tid] += t;
        __syncthreads();
    }
    if (tid < NPBF) {
        int ex = start[tid] - hist[tid];
        start[tid] = ex;
        cursor[tid] = ex;
    }
    __syncthreads();

    // pass B: ranked LDS->LDS scatter
    for (int k = tid; k < stored; k += 1024) {
        unsigned p = raw[k];
        int pos = atomicAdd(&cursor[p >> 23], 1);
        srt[pos] = (int)(p & SRC_MASK);
    }
    __syncthreads();

    // gather: 8 lanes per node, f32 accumulate, bf16 store; 8-deep unroll
    int g = tid & 7;
    const bf16x8* f8 = reinterpret_cast<const bf16x8*>(featb);
    for (int ln = tid >> 3; ln < npb; ln += 128) {
        int node = node0 + ln;
        if (node >= n) break;
        bf16x8 self = f8[node * 8 + g];
        float acc[8];
#pragma unroll
        for (int j = 0; j < 8; ++j) acc[j] = (float)self[j];

        int s0 = start[ln];
        int e1 = s0 + hist[ln];
        int i = s0;
        for (; i + 8 <= e1; i += 8) {
            bf16x8 v0 = f8[srt[i + 0] * 8 + g];
            bf16x8 v1 = f8[srt[i + 1] * 8 + g];
            bf16x8 v2 = f8[srt[i + 2] * 8 + g];
            bf16x8 v3 = f8[srt[i + 3] * 8 + g];
            bf16x8 v4 = f8[srt[i + 4] * 8 + g];
            bf16x8 v5 = f8[srt[i + 5] * 8 + g];
            bf16x8 v6 = f8[srt[i + 6] * 8 + g];
            bf16x8 v7 = f8[srt[i + 7] * 8 + g];
#pragma unroll
            for (int j = 0; j < 8; ++j)
                acc[j] += (((float)v0[j] + (float)v1[j]) +
                           ((float)v2[j] + (float)v3[j])) +
                          (((float)v4[j] + (float)v5[j]) +
                           ((float)v6[j] + (float)v7[j]));
        }
        for (; i + 4 <= e1; i += 4) {
            bf16x8 v0 = f8[srt[i + 0] * 8 + g];
            bf16x8 v1 = f8[srt[i + 1] * 8 + g];
            bf16x8 v2 = f8[srt[i + 2] * 8 + g];
            bf16x8 v3 = f8[srt[i + 3] * 8 + g];
#pragma unroll
            for (int j = 0; j < 8; ++j)
                acc[j] += ((float)v0[j] + (float)v1[j]) +
                          ((float)v2[j] + (float)v3[j]);
        }
        for (; i < e1; ++i) {
            bf16x8 v = f8[srt[i] * 8 + g];
#pragma unroll
            for (int j = 0; j < 8; ++j) acc[j] += (float)v[j];
        }
        if (ovfn > 0) {   // rare-path correctness: scan spilled edges
            unsigned key = ((unsigned)b << 16) | (unsigned)ln;
            for (int k = 0; k < ovfn; ++k) {
                uint2 oe = ovf[k];
                if (oe.x == key) {
                    bf16x8 v = f8[oe.y * 8 + g];
#pragma unroll
                    for (int j = 0; j < 8; ++j) acc[j] += (float)v[j];
                }
            }
        }

        uint4v o = { pack_bf16x2(acc[0], acc[1]), pack_bf16x2(acc[2], acc[3]),
                     pack_bf16x2(acc[4], acc[5]), pack_bf16x2(acc[6], acc[7]) };
        reinterpret_cast<uint4v*>(rstb)[node * 8 + g] = o;
    }
}

// ===========================================================================
// TIER 2 — round-8 proven path (used when ws too small for tier 1)
// ===========================================================================
__global__ void prep_weights_kernel(const float* __restrict__ W1,
                                    const float* __restrict__ W2,
                                    bf16x8* __restrict__ wf,
                                    int* __restrict__ gz) {
    if (blockIdx.x >= 64) {
        for (int i = threadIdx.x; i < 2 * NB2; i += 64) gz[i] = 0;
        return;
    }
    wf[blockIdx.x * 64 + threadIdx.x] =
        weight_frag(W1, W2, blockIdx.x, threadIdx.x);
}

__global__ __launch_bounds__(256) void cvt_hist_kernel(
        const float* __restrict__ feat, unsigned short* __restrict__ featb,
        int n8, const int* __restrict__ dst, int E, int* __restrict__ gcnt,
        int npb, int nb, int cvtB) {
    int tid = threadIdx.x;
    if ((int)blockIdx.x < cvtB) {
        int i = blockIdx.x * 256 + tid;
        if (i < n8) {
            const float4* f4 = reinterpret_cast<const float4*>(feat);
            float4 a = f4[2 * i];
            float4 b = f4[2 * i + 1];
            uint4v o = { pack_bf16x2(a.x, a.y), pack_bf16x2(a.z, a.w),
                         pack_bf16x2(b.x, b.y), pack_bf16x2(b.z, b.w) };
            reinterpret_cast<uint4v*>(featb)[i] = o;
        }
    } else {
        __shared__ int c[NB2];
        for (int i = tid; i < NB2; i += 256) c[i] = 0;
        __syncthreads();
        int hb = gridDim.x - cvtB;
        for (int e = (blockIdx.x - cvtB) * 256 + tid; e < E; e += hb * 256)
            atomicAdd(&c[(unsigned)dst[e] / (unsigned)npb], 1);
        __syncthreads();
        for (int i = tid; i < nb; i += 256)
            if (c[i] > 0) atomicAdd(&gcnt[i], c[i]);
    }
}

__global__ __launch_bounds__(1024) void partition2_kernel(
        const int* __restrict__ src, const int* __restrict__ dst,
        const int* __restrict__ gcnt, int* __restrict__ cur2,
        unsigned* __restrict__ packed, int E, int npb, int nb) {
    __shared__ int sg[NB2];
    __shared__ int cnt[NB2];
    __shared__ int base_s[NB2];
    int tid = threadIdx.x;
    if (tid < NB2) {
        sg[tid] = (tid < nb) ? gcnt[tid] : 0;
        cnt[tid] = 0;
    }
    __syncthreads();
    for (int o = 1; o < NB2; o <<= 1) {
        int t = (tid < NB2 && tid >= o) ? sg[tid - o] : 0;
        __syncthreads();
        if (tid < NB2) sg[tid] += t;
        __syncthreads();
    }
    int e0 = blockIdx.x * (1024 * PEPT);
    unsigned myP[PEPT];
    int myB[PEPT], myR[PEPT];
#pragma unroll
    for (int j = 0; j < PEPT; ++j) {
        int e = e0 + j * 1024 + tid;
        if (e < E) {
            int d = dst[e];
            int s = src[e];
            int b = (unsigned)d / (unsigned)npb;
            myB[j] = b;
            myR[j] = atomicAdd(&cnt[b], 1);
            myP[j] = ((unsigned)(d - b * npb) << 23) | (unsigned)s;
        } else {
            myB[j] = -1;
        }
    }
    __syncthreads();
    if (tid < nb && cnt[tid] > 0)
        base_s[tid] = (sg[tid] - gcnt[tid]) + atomicAdd(&cur2[tid], cnt[tid]);
    __syncthreads();
#pragma unroll
    for (int j = 0; j < PEPT; ++j) {
        if (myB[j] >= 0) packed[base_s[myB[j]] + myR[j]] = myP[j];
    }
}

__global__ __launch_bounds__(1024, 2) void csr_gather2_kernel(
        const unsigned* __restrict__ packed, const int* __restrict__ gcnt,
        const unsigned short* __restrict__ featb,
        int* __restrict__ csr_g, unsigned short* __restrict__ rstb,
        int n, int npb, int nb) {
    __shared__ int sg[NB2];
    __shared__ int hist[NPB2];
    __shared__ int start[NPB2];
    __shared__ int cursor[NPB2];
    __shared__ unsigned raw[CAP2];
    __shared__ int srt[CAP2];

    int b = blockIdx.x;
    int tid = threadIdx.x;
    int node0 = b * npb;

    if (tid < NB2) sg[tid] = (tid < nb) ? gcnt[tid] : 0;
    if (tid < NPB2) hist[tid] = 0;
    __syncthreads();
    for (int o = 1; o < NB2; o <<= 1) {
        int t = (tid < NB2 && tid >= o) ? sg[tid - o] : 0;
        __syncthreads();
        if (tid < NB2) sg[tid] += t;
        __syncthreads();
    }
    int ie = sg[b];
    int ib = (b > 0) ? sg[b - 1] : 0;
    bool useG = (ie - ib) > CAP2;

    for (int k = ib + tid; k < ie; k += 1024) {
        unsigned p = packed[k];
        if (!useG) raw[k - ib] = p;
        atomicAdd(&hist[p >> 23], 1);
    }
    __syncthreads();

    if (tid < NPB2) start[tid] = hist[tid];
    __syncthreads();
    for (int o = 1; o < NPB2; o <<= 1) {
        int t = (tid < NPB2 && tid >= o) ? start[tid - o] : 0;
        __syncthreads();
        if (tid < NPB2) start[tid] += t;
        __syncthreads();
    }
    if (tid < NPB2) {
        int excl = start[tid] - hist[tid];
        start[tid] = excl;
        cursor[tid] = excl;
    }
    __syncthreads();

    int cnt_e = ie - ib;
    if (!useG) {
        for (int k = tid; k < cnt_e; k += 1024) {
            unsigned p = raw[k];
            int pos = atomicAdd(&cursor[p >> 23], 1);
            srt[pos] = (int)(p & SRC_MASK);
        }
    } else {
        for (int k = ib + tid; k < ie; k += 1024) {
            unsigned p = packed[k];
            int pos = atomicAdd(&cursor[p >> 23], 1);
            csr_g[ib + pos] = (int)(p & SRC_MASK);
        }
    }
    __syncthreads();

    int g = tid & 7;
    const bf16x8* f8 = reinterpret_cast<const bf16x8*>(featb);
    for (int ln = tid >> 3; ln < npb; ln += 128) {
        int node = node0 + ln;
        if (node >= n) break;
        bf16x8 self = f8[node * 8 + g];
        float acc[8];
#pragma unroll
        for (int j = 0; j < 8; ++j) acc[j] = (float)self[j];

        int s0 = start[ln];
        int e1 = s0 + hist[ln];
        const int* lst = useG ? (csr_g + ib) : srt;
        int i = s0;
        for (; i + 4 <= e1; i += 4) {
            int u0 = lst[i + 0];
            int u1 = lst[i + 1];
            int u2 = lst[i + 2];
            int u3 = lst[i + 3];
            bf16x8 v0 = f8[u0 * 8 + g];
            bf16x8 v1 = f8[u1 * 8 + g];
            bf16x8 v2 = f8[u2 * 8 + g];
            bf16x8 v3 = f8[u3 * 8 + g];
#pragma unroll
            for (int j = 0; j < 8; ++j)
                acc[j] += ((float)v0[j] + (float)v1[j]) +
                          ((float)v2[j] + (float)v3[j]);
        }
        for (; i < e1; ++i) {
            bf16x8 v = f8[lst[i] * 8 + g];
#pragma unroll
            for (int j = 0; j < 8; ++j) acc[j] += (float)v[j];
        }

        uint4v o = { pack_bf16x2(acc[0], acc[1]), pack_bf16x2(acc[2], acc[3]),
                     pack_bf16x2(acc[4], acc[5]), pack_bf16x2(acc[6], acc[7]) };
        reinterpret_cast<uint4v*>(rstb)[node * 8 + g] = o;
    }
}

// ===========================================================================
// Fused MFMA MLP: out^T = W2^T @ relu(W1^T @ rst^T + b1) + b2
// (round-9-proven form: 1 tile/wave, 391 blocks)
// ===========================================================================
template <bool BF16>
__global__ __launch_bounds__(512, 4) void mlp_mfma_kernel(
        const void* __restrict__ rstv, const bf16x8* __restrict__ wf,
        const float* __restrict__ b1, const float* __restrict__ b2,
        float* __restrict__ out, int n, int ntiles) {
    __shared__ bf16x8 swf[64 * 64];   // 64 KiB
    __shared__ float sb1[H];
    __shared__ float sb2[D];

    for (int i = threadIdx.x; i < 64 * 64; i += 512) swf[i] = wf[i];
    if (threadIdx.x < H) sb1[threadIdx.x] = b1[threadIdx.x];
    if (threadIdx.x < D) sb2[threadIdx.x] = b2[threadIdx.x];
    __syncthreads();

    int lane = threadIdx.x & 63;
    int wid  = threadIdx.x >> 6;
    int g = lane >> 5, c = lane & 31;

    int tile = blockIdx.x * 8 + wid;
    if (tile >= ntiles) return;
    int node = tile * 32 + c;
    bool valid = node < n;
    int nodeC = valid ? node : (n - 1);

    bf16x8 bfr[4];
    if constexpr (BF16) {
        const bf16x8* rb = reinterpret_cast<const bf16x8*>(rstv) +
                           (size_t)nodeC * 8 + g;
#pragma unroll
        for (int ks = 0; ks < 4; ++ks) bfr[ks] = rb[2 * ks];
    } else {
        const float* rrow = reinterpret_cast<const float*>(rstv) +
                            (size_t)nodeC * D + 8 * g;
#pragma unroll
        for (int ks = 0; ks < 4; ++ks) {
            float4 lo = *reinterpret_cast<const float4*>(rrow + 16 * ks);
            float4 hi = *reinterpret_cast<const float4*>(rrow + 16 * ks + 4);
            bf16x8 v;
            v[0] = (__bf16)lo.x; v[1] = (__bf16)lo.y; v[2] = (__bf16)lo.z; v[3] = (__bf16)lo.w;
            v[4] = (__bf16)hi.x; v[5] = (__bf16)hi.y; v[6] = (__bf16)hi.z; v[7] = (__bf16)hi.w;
            bfr[ks] = v;
        }
    }

    f32x16 acc2_0 = {};
    f32x16 acc2_1 = {};

#pragma unroll
    for (int ht = 0; ht < 8; ++ht) {
        f32x16 a1 = {};
#pragma unroll
        for (int ks = 0; ks < 4; ++ks)
            a1 = __builtin_amdgcn_mfma_f32_32x32x16_bf16(
                     swf[(ht * 4 + ks) * 64 + lane], bfr[ks], a1, 0, 0, 0);

        float hv[16];
#pragma unroll
        for (int q = 0; q < 4; ++q) {
            float4 bq = *reinterpret_cast<const float4*>(&sb1[32 * ht + 8 * q + 4 * g]);
            hv[4 * q + 0] = fmaxf(a1[4 * q + 0] + bq.x, 0.0f);
            hv[4 * q + 1] = fmaxf(a1[4 * q + 1] + bq.y, 0.0f);
            hv[4 * q + 2] = fmaxf(a1[4 * q + 2] + bq.z, 0.0f);
            hv[4 * q + 3] = fmaxf(a1[4 * q + 3] + bq.w, 0.0f);
        }

#pragma unroll
        for (int half = 0; half < 2; ++half) {
            const float* hs = hv + 8 * half;
            unsigned plo0 = pack_bf16x2(hs[0], hs[1]);
            unsigned plo1 = pack_bf16x2(hs[2], hs[3]);
            unsigned phi0 = pack_bf16x2(hs[4], hs[5]);
            unsigned phi1 = pack_bf16x2(hs[6], hs[7]);
            unsigned f0, f2, f1, f3;
            lane32_swap(plo0, phi0, f0, f2);
            lane32_swap(plo1, phi1, f1, f3);
            uint4v fr = { f0, f1, f2, f3 };
            bf16x8 b2f = __builtin_bit_cast(bf16x8, fr);
            int ks2 = 2 * ht + half;
            acc2_0 = __builtin_amdgcn_mfma_f32_32x32x16_bf16(
                         swf[(32 + 0 * 16 + ks2) * 64 + lane], b2f, acc2_0, 0, 0, 0);
            acc2_1 = __builtin_amdgcn_mfma_f32_32x32x16_bf16(
                         swf[(32 + 1 * 16 + ks2) * 64 + lane], b2f, acc2_1, 0, 0, 0);
        }
    }

    if (!valid) return;
    float* orow = out + (size_t)node * D;
#pragma unroll
    for (int dt = 0; dt < 2; ++dt) {
        const f32x16& a = dt ? acc2_1 : acc2_0;
#pragma unroll
        for (int q = 0; q < 4; ++q) {
            int d0 = 32 * dt + 8 * q + 4 * g;
            float4 bq = *reinterpret_cast<const float4*>(&sb2[d0]);
            float4 v;
            v.x = a[4 * q + 0] + bq.x;
            v.y = a[4 * q + 1] + bq.y;
            v.z = a[4 * q + 2] + bq.z;
            v.w = a[4 * q + 3] + bq.w;
            *reinterpret_cast<float4*>(orow + d0) = v;
        }
    }
}

// ===========================================================================
// TIER 3 — atomic fallback
// ===========================================================================
__global__ void copy_feat_kernel(const float* __restrict__ feat,
                                 float* __restrict__ rst, int n4) {
    int i = blockIdx.x * blockDim.x + threadIdx.x;
    if (i < n4) {
        reinterpret_cast<float4*>(rst)[i] =
            reinterpret_cast<const float4*>(feat)[i];
    }
}

__global__ void scatter_add_kernel(const float* __restrict__ feat,
                                   const int* __restrict__ src,
                                   const int* __restrict__ dst,
                                   float* rst, int E) {
    int gid = blockIdx.x * blockDim.x + threadIdx.x;
    int e = gid >> 4;
    if (e >= E) return;
    int d4 = (gid & 15) << 2;
    int s = src[e];
    int t = dst[e];
    float4 v = *reinterpret_cast<const float4*>(&feat[s * D + d4]);
    float* p = &rst[t * D + d4];
    atomicAdd(p + 0, v.x);
    atomicAdd(p + 1, v.y);
    atomicAdd(p + 2, v.z);
    atomicAdd(p + 3, v.w);
}

__global__ __launch_bounds__(512) void mlp_valu_kernel(
        const float* rst,
        const float* __restrict__ W1, const float* __restrict__ b1,
        const float* __restrict__ W2, const float* __restrict__ b2,
        float* out, int n) {
    __shared__ float sW1t[H * D];
    __shared__ float sW2 [H * D];
    __shared__ float sb1[H];
    __shared__ float sb2[D];

    for (int i = threadIdx.x; i < D * H; i += 512) {
        int d = i >> 8;
        int j = i & (H - 1);
        sW1t[j * D + d] = W1[i];
        sW2[i] = W2[i];
    }
    if (threadIdx.x < H) sb1[threadIdx.x] = b1[threadIdx.x];
    if (threadIdx.x < D) sb2[threadIdx.x] = b2[threadIdx.x];
    __syncthreads();

    int node = blockIdx.x * 512 + threadIdx.x;
    if (node >= n) return;

    float x[D];
    const float4* xr = reinterpret_cast<const float4*>(&rst[node * D]);
#pragma unroll
    for (int d4 = 0; d4 < D / 4; ++d4) {
        float4 v = xr[d4];
        x[d4 * 4 + 0] = v.x; x[d4 * 4 + 1] = v.y;
        x[d4 * 4 + 2] = v.z; x[d4 * 4 + 3] = v.w;
    }
    float acc[D];
#pragma unroll
    for (int d = 0; d < D; ++d) acc[d] = sb2[d];
    for (int j = 0; j < H; ++j) {
        float h = sb1[j];
        const float4* w1 = reinterpret_cast<const float4*>(&sW1t[j * D]);
#pragma unroll
        for (int d4 = 0; d4 < D / 4; ++d4) {
            float4 w = w1[d4];
            h += x[d4 * 4 + 0] * w.x + x[d4 * 4 + 1] * w.y +
                 x[d4 * 4 + 2] * w.z + x[d4 * 4 + 3] * w.w;
        }
        h = fmaxf(h, 0.0f);
        const float4* w2 = reinterpret_cast<const float4*>(&sW2[j * D]);
#pragma unroll
        for (int d4 = 0; d4 < D / 4; ++d4) {
            float4 w = w2[d4];
            acc[d4 * 4 + 0] += h * w.x; acc[d4 * 4 + 1] += h * w.y;
            acc[d4 * 4 + 2] += h * w.z; acc[d4 * 4 + 3] += h * w.w;
        }
    }
    float4* op = reinterpret_cast<float4*>(&out[node * D]);
#pragma unroll
    for (int d4 = 0; d4 < D / 4; ++d4) {
        float4 v;
        v.x = acc[d4 * 4 + 0]; v.y = acc[d4 * 4 + 1];
        v.z = acc[d4 * 4 + 2]; v.w = acc[d4 * 4 + 3];
        op[d4] = v;
    }
}

// ===========================================================================
extern "C" void kernel_launch(void* const* d_in, const int* in_sizes, int n_in,
                              void* d_out, int out_size, void* d_ws, size_t ws_size,
                              hipStream_t stream) {
    const float* feat = (const float*)d_in[0];
    const float* W1   = (const float*)d_in[1];
    const float* b1   = (const float*)d_in[2];
    const float* W2   = (const float*)d_in[3];
    const float* b2   = (const float*)d_in[4];
    const int*   src  = (const int*)d_in[5];
    const int*   dst  = (const int*)d_in[6];
    float* buf = (float*)d_out;

    int n = in_sizes[0] / D;
    int E = in_sizes[5];
    char* ws = (char*)d_ws;

    // ---------- tier 1 layout ----------
    int npbF = (n + NBF - 1) / NBF;
    int nbF  = (n + npbF - 1) / npbF;
    size_t o1 = 0;
    auto a1 = [&](size_t bytes) { size_t c = o1; o1 = (o1 + bytes + 255) & ~(size_t)255; return c; };
    size_t t1_wf     = a1(64 * 64 * sizeof(bf16x8));
    size_t t1_ctrl   = a1((NBF + 1) * sizeof(int));
    size_t t1_packed = a1((size_t)NBF * CAPF * sizeof(unsigned));
    size_t t1_ovf    = a1((size_t)E * sizeof(uint2));
    size_t t1_featb  = a1((size_t)n * D * 2);
    size_t t1_rstb   = a1((size_t)n * D * 2);
    size_t need1 = o1;
    bool tier1 = (npbF <= NPBF) && (ws_size >= need1);

    if (tier1) {
        bf16x8*   wf     = (bf16x8*)(ws + t1_wf);
        int*      ctrl   = (int*)(ws + t1_ctrl);
        unsigned* packed = (unsigned*)(ws + t1_packed);
        uint2*    ovf    = (uint2*)(ws + t1_ovf);
        unsigned short* featb = (unsigned short*)(ws + t1_featb);
        unsigned short* rstb  = (unsigned short*)(ws + t1_rstb);

        hipMemsetAsync(ctrl, 0, (NBF + 1) * sizeof(int), stream);

        int n8v  = n * D / 8;
        int cvtB = (n8v + 1023) / 1024;
        int pB   = (E + 1024 * PJ - 1) / (1024 * PJ);
        int prepB = 4;
        fused_front_kernel<<<pB + prepB + cvtB, 1024, 0, stream>>>(
            feat, featb, n8v, W1, W2, wf, src, dst, ctrl, packed, ovf,
            E, npbF, pB, prepB);

        csr_gather_fixed_kernel<<<nbF, 1024, 0, stream>>>(
            packed, ctrl, ovf, featb, rstb, n, npbF);

        int ntiles = (n + 31) / 32;
        mlp_mfma_kernel<true><<<(ntiles + 7) / 8, 512, 0, stream>>>(
            rstb, wf, b1, b2, buf, n, ntiles);
        return;
    }

    // ---------- tier 2 layout (round-8 path) ----------
    int npb2 = (n + NB2 - 1) / NB2;
    int nb2  = (n + npb2 - 1) / npb2;
    size_t o2 = 0;
    auto a2 = [&](size_t bytes) { size_t c = o2; o2 = (o2 + bytes + 255) & ~(size_t)255; return c; };
    size_t t2_wf     = a2(64 * 64 * sizeof(bf16x8));
    size_t t2_gcnt   = a2(2 * NB2 * sizeof(int));
    size_t t2_packed = a2((size_t)E * sizeof(unsigned));
    size_t t2_csrg   = a2((size_t)E * sizeof(int));
    size_t t2_featb  = a2((size_t)n * D * 2);
    size_t t2_rstb   = a2((size_t)n * D * 2);
    size_t need2 = o2;
    bool haveWf = ws_size >= 64 * 64 * sizeof(bf16x8);
    bool tier2  = (npb2 <= NPB2) && (n < (1 << 23)) && (ws_size >= need2);

    if (tier2) {
        bf16x8*   wf     = (bf16x8*)(ws + t2_wf);
        int*      gcnt   = (int*)(ws + t2_gcnt);
        int*      cur2   = gcnt + NB2;
        unsigned* packed = (unsigned*)(ws + t2_packed);
        int*      csr_g  = (int*)(ws + t2_csrg);
        unsigned short* featb = (unsigned short*)(ws + t2_featb);
        unsigned short* rstb  = (unsigned short*)(ws + t2_rstb);

        prep_weights_kernel<<<65, 64, 0, stream>>>(W1, W2, wf, gcnt);

        int n8   = n * D / 8;
        int cvtB = (n8 + 255) / 256;
        cvt_hist_kernel<<<cvtB + 784, 256, 0, stream>>>(
            feat, featb, n8, dst, E, gcnt, npb2, nb2, cvtB);

        int pB2 = (E + 1024 * PEPT - 1) / (1024 * PEPT);
        partition2_kernel<<<pB2, 1024, 0, stream>>>(
            src, dst, gcnt, cur2, packed, E, npb2, nb2);

        csr_gather2_kernel<<<nb2, 1024, 0, stream>>>(
            packed, gcnt, featb, csr_g, rstb, n, npb2, nb2);

        int ntiles = (n + 31) / 32;
        mlp_mfma_kernel<true><<<(ntiles + 7) / 8, 512, 0, stream>>>(
            rstb, wf, b1, b2, buf, n, ntiles);
        return;
    }

    // ---------- tier 3: atomic fallback ----------
    if (haveWf) {
        bf16x8* wf = (bf16x8*)ws;
        prep_weights_kernel<<<64, 64, 0, stream>>>(W1, W2, wf, (int*)ws);
        int n4 = n * D / 4;
        copy_feat_kernel<<<(n4 + 255) / 256, 256, 0, stream>>>(feat, buf, n4);
        int threads = E * 16;
        scatter_add_kernel<<<(threads + 255) / 256, 256, 0, stream>>>(
            feat, src, dst, buf, E);
        int ntiles = (n + 31) / 32;
        mlp_mfma_kernel<false><<<(ntiles + 7) / 8, 512, 0, stream>>>(
            buf, wf, b1, b2, buf, n, ntiles);
    } else {
        int n4 = n * D / 4;
        copy_feat_kernel<<<(n4 + 255) / 256, 256, 0, stream>>>(feat, buf, n4);
        int threads = E * 16;
        scatter_add_kernel<<<(threads + 255) / 256, 256, 0, stream>>>(
            feat, src, dst, buf, E);
        mlp_valu_kernel<<<(n + 511) / 512, 512, 0, stream>>>(
            buf, W1, b1, W2, b2, buf, n);
    }
}

// Round 15
// 75.409 us; speedup vs baseline: 1.0710x; 1.0604x over previous
//
#include <hip/hip_runtime.h>

#define D 64
#define H 256
#define SRC_MASK ((1u << 23) - 1)

// ---- tier-1 (fixed-capacity) params ----
#define NBF 512             // buckets
#define NPBF 256            // max nodes per bucket
#define CAPF 4096           // packed slots per bucket
#define PJ 8                // partition: edges per thread

// ---- tier-2 (round-8 proven path) params ----
#define NB2 512
#define NPB2 256
#define CAP2 6144
#define PEPT 16

typedef __bf16 bf16x8 __attribute__((ext_vector_type(8)));
typedef float f32x16 __attribute__((ext_vector_type(16)));
typedef unsigned int uint4v __attribute__((ext_vector_type(4)));

__device__ inline unsigned pack_bf16x2(float a, float b) {
    unsigned short ua = __builtin_bit_cast(unsigned short, (__bf16)a);
    unsigned short ub = __builtin_bit_cast(unsigned short, (__bf16)b);
    return (unsigned)ua | ((unsigned)ub << 16);
}

__device__ inline void lane32_swap(unsigned x, unsigned y, unsigned& o0, unsigned& o1) {
#if __has_builtin(__builtin_amdgcn_permlane32_swap)
    typedef unsigned int uint2v __attribute__((ext_vector_type(2)));
    uint2v r = __builtin_amdgcn_permlane32_swap(x, y, false, false);
    o0 = r.x; o1 = r.y;
#else
    unsigned xs = __shfl_xor((int)x, 32, 64);
    unsigned ys = __shfl_xor((int)y, 32, 64);
    bool hi = (threadIdx.x & 32) != 0;
    o0 = hi ? ys : x;
    o1 = hi ? y : xs;
#endif
}

// ===========================================================================
// Device helper: compute one weight fragment
// ===========================================================================
__device__ inline bf16x8 weight_frag(const float* __restrict__ W1,
                                     const float* __restrict__ W2,
                                     int fid, int lane) {
    int g = lane >> 5, c = lane & 31;
    bf16x8 v;
    if (fid < 32) {
        int ht = fid >> 2, ks = fid & 3;
        const float* col = W1 + (32 * ht + c);
        int k0 = 16 * ks + 8 * g;
#pragma unroll
        for (int j = 0; j < 8; ++j) v[j] = (__bf16)col[(size_t)(k0 + j) * H];
    } else {
        int f = fid - 32;
        int dt = f >> 4, ks = f & 15;
        const float* col = W2 + (32 * dt + c);
        int k0 = 16 * ks + 8 * g;
#pragma unroll
        for (int j = 0; j < 8; ++j) v[j] = (__bf16)col[(size_t)(k0 + j) * D];
    }
    return v;
}

// ===========================================================================
// TIER 1 — K-A) fused front-end: partition (blocks [0,pB)) |
//                weight prep | cvt. Partition blocks scheduled first.
// ===========================================================================
__global__ __launch_bounds__(1024) void fused_front_kernel(
        const float* __restrict__ feat, unsigned short* __restrict__ featb,
        int n8v,
        const float* __restrict__ W1, const float* __restrict__ W2,
        bf16x8* __restrict__ wf,
        const int* __restrict__ src, const int* __restrict__ dst,
        int* __restrict__ cur,           // [NBF] cursors, [NBF] = ovf count
        unsigned* __restrict__ packed, uint2* __restrict__ ovf,
        int E, int npb, int pB, int prepB) {
    int blk = blockIdx.x;
    int tid = threadIdx.x;

    if (blk >= pB + prepB) {
        int i = (blk - pB - prepB) * 1024 + tid;
        if (i < n8v) {
            const float4* f4 = reinterpret_cast<const float4*>(feat);
            float4 a = f4[2 * i];
            float4 b = f4[2 * i + 1];
            uint4v o = { pack_bf16x2(a.x, a.y), pack_bf16x2(a.z, a.w),
                         pack_bf16x2(b.x, b.y), pack_bf16x2(b.z, b.w) };
            reinterpret_cast<uint4v*>(featb)[i] = o;
        }
        return;
    }
    if (blk >= pB) {
        int fid = (blk - pB) * 16 + (tid >> 6);
        int lane = tid & 63;
        if (fid < 64) wf[fid * 64 + lane] = weight_frag(W1, W2, fid, lane);
        return;
    }

    // ---- partition: one round of PJ edges/thread ----
    __shared__ int cnt[NBF];
    __shared__ int resv[NBF];
    if (tid < NBF) cnt[tid] = 0;
    __syncthreads();
    int e0 = blk * (1024 * PJ);
    unsigned myP[PJ];
    int myB[PJ], myR[PJ];
#pragma unroll
    for (int j = 0; j < PJ; ++j) {
        int e = e0 + j * 1024 + tid;
        if (e < E) {
            int d = dst[e];
            int s = src[e];
            int b = (int)((unsigned)d / (unsigned)npb);
            myB[j] = b;
            myR[j] = atomicAdd(&cnt[b], 1);
            myP[j] = ((unsigned)(d - b * npb) << 23) | (unsigned)s;
        } else {
            myB[j] = -1;
        }
    }
    __syncthreads();
    if (tid < NBF && cnt[tid] > 0)
        resv[tid] = atomicAdd(&cur[tid], cnt[tid]);
    __syncthreads();
#pragma unroll
    for (int j = 0; j < PJ; ++j) {
        if (myB[j] < 0) continue;
        int slot = resv[myB[j]] + myR[j];
        if (slot < CAPF) {
            packed[(size_t)myB[j] * CAPF + slot] = myP[j];
        } else {
            int oi = atomicAdd(&cur[NBF], 1);
            ovf[oi] = make_uint2(((unsigned)myB[j] << 16) | (myP[j] >> 23),
                                 myP[j] & SRC_MASK);
        }
    }
}

// ===========================================================================
// TIER 1 — K-B) per-bucket counting sort (LDS) + single-pass gather.
// 8 lanes/node, 16 B bf16x8 loads, f32 accumulate, bf16 store.
// ===========================================================================
__global__ __launch_bounds__(1024, 2) void csr_gather_fixed_kernel(
        const unsigned* __restrict__ packed, const int* __restrict__ cur,
        const uint2* __restrict__ ovf,
        const unsigned short* __restrict__ featb,
        unsigned short* __restrict__ rstb, int n, int npb) {
    __shared__ int hist[NPBF];
    __shared__ int start[NPBF];
    __shared__ int cursor[NPBF];
    __shared__ unsigned raw[CAPF];
    __shared__ int srt[CAPF];

    int b = blockIdx.x;
    int tid = threadIdx.x;
    int node0 = b * npb;

    if (tid < NPBF) hist[tid] = 0;
    __syncthreads();

    int stored = cur[b];
    if (stored > CAPF) stored = CAPF;
    int ovfn = cur[NBF];
    const unsigned* win = packed + (size_t)b * CAPF;

    // pass A: window -> LDS raw + per-node histogram (NT: read-once stream)
    for (int k = tid; k < stored; k += 1024) {
        unsigned p = __builtin_nontemporal_load(win + k);
        raw[k] = p;
        atomicAdd(&hist[p >> 23], 1);
    }
    __syncthreads();

    // 256-entry scan
    if (tid < NPBF) start[tid] = hist[tid];
    __syncthreads();
    for (int o = 1; o < NPBF; o <<= 1) {
        int t = (tid < NPBF && tid >= o) ? start[tid - o] : 0;
        __syncthreads();
        if (tid < NPBF) start[tid] += t;
        __syncthreads();
    }
    if (tid < NPBF) {
        int ex = start[tid] - hist[tid];
        start[tid] = ex;
        cursor[tid] = ex;
    }
    __syncthreads();

    // pass B: ranked LDS->LDS scatter
    for (int k = tid; k < stored; k += 1024) {
        unsigned p = raw[k];
        int pos = atomicAdd(&cursor[p >> 23], 1);
        srt[pos] = (int)(p & SRC_MASK);
    }
    __syncthreads();

    // gather: 8 lanes per node, f32 accumulate, bf16 store
    int g = tid & 7;
    const bf16x8* f8 = reinterpret_cast<const bf16x8*>(featb);
    for (int ln = tid >> 3; ln < npb; ln += 128) {
        int node = node0 + ln;
        if (node >= n) break;
        bf16x8 self = f8[node * 8 + g];
        float acc[8];
#pragma unroll
        for (int j = 0; j < 8; ++j) acc[j] = (float)self[j];

        int s0 = start[ln];
        int e1 = s0 + hist[ln];
        int i = s0;
        for (; i + 4 <= e1; i += 4) {
            int u0 = srt[i + 0];
            int u1 = srt[i + 1];
            int u2 = srt[i + 2];
            int u3 = srt[i + 3];
            bf16x8 v0 = f8[u0 * 8 + g];
            bf16x8 v1 = f8[u1 * 8 + g];
            bf16x8 v2 = f8[u2 * 8 + g];
            bf16x8 v3 = f8[u3 * 8 + g];
#pragma unroll
            for (int j = 0; j < 8; ++j)
                acc[j] += ((float)v0[j] + (float)v1[j]) +
                          ((float)v2[j] + (float)v3[j]);
        }
        for (; i < e1; ++i) {
            bf16x8 v = f8[srt[i] * 8 + g];
#pragma unroll
            for (int j = 0; j < 8; ++j) acc[j] += (float)v[j];
        }
        if (ovfn > 0) {   // rare-path correctness: scan spilled edges
            unsigned key = ((unsigned)b << 16) | (unsigned)ln;
            for (int k = 0; k < ovfn; ++k) {
                uint2 oe = ovf[k];
                if (oe.x == key) {
                    bf16x8 v = f8[oe.y * 8 + g];
#pragma unroll
                    for (int j = 0; j < 8; ++j) acc[j] += (float)v[j];
                }
            }
        }

        uint4v o = { pack_bf16x2(acc[0], acc[1]), pack_bf16x2(acc[2], acc[3]),
                     pack_bf16x2(acc[4], acc[5]), pack_bf16x2(acc[6], acc[7]) };
        reinterpret_cast<uint4v*>(rstb)[node * 8 + g] = o;
    }
}

// ===========================================================================
// TIER 2 — round-8 proven path (used when ws too small for tier 1)
// ===========================================================================
__global__ void prep_weights_kernel(const float* __restrict__ W1,
                                    const float* __restrict__ W2,
                                    bf16x8* __restrict__ wf,
                                    int* __restrict__ gz) {
    if (blockIdx.x >= 64) {
        for (int i = threadIdx.x; i < 2 * NB2; i += 64) gz[i] = 0;
        return;
    }
    wf[blockIdx.x * 64 + threadIdx.x] =
        weight_frag(W1, W2, blockIdx.x, threadIdx.x);
}

__global__ __launch_bounds__(256) void cvt_hist_kernel(
        const float* __restrict__ feat, unsigned short* __restrict__ featb,
        int n8, const int* __restrict__ dst, int E, int* __restrict__ gcnt,
        int npb, int nb, int cvtB) {
    int tid = threadIdx.x;
    if ((int)blockIdx.x < cvtB) {
        int i = blockIdx.x * 256 + tid;
        if (i < n8) {
            const float4* f4 = reinterpret_cast<const float4*>(feat);
            float4 a = f4[2 * i];
            float4 b = f4[2 * i + 1];
            uint4v o = { pack_bf16x2(a.x, a.y), pack_bf16x2(a.z, a.w),
                         pack_bf16x2(b.x, b.y), pack_bf16x2(b.z, b.w) };
            reinterpret_cast<uint4v*>(featb)[i] = o;
        }
    } else {
        __shared__ int c[NB2];
        for (int i = tid; i < NB2; i += 256) c[i] = 0;
        __syncthreads();
        int hb = gridDim.x - cvtB;
        for (int e = (blockIdx.x - cvtB) * 256 + tid; e < E; e += hb * 256)
            atomicAdd(&c[(unsigned)dst[e] / (unsigned)npb], 1);
        __syncthreads();
        for (int i = tid; i < nb; i += 256)
            if (c[i] > 0) atomicAdd(&gcnt[i], c[i]);
    }
}

__global__ __launch_bounds__(1024) void partition2_kernel(
        const int* __restrict__ src, const int* __restrict__ dst,
        const int* __restrict__ gcnt, int* __restrict__ cur2,
        unsigned* __restrict__ packed, int E, int npb, int nb) {
    __shared__ int sg[NB2];
    __shared__ int cnt[NB2];
    __shared__ int base_s[NB2];
    int tid = threadIdx.x;
    if (tid < NB2) {
        sg[tid] = (tid < nb) ? gcnt[tid] : 0;
        cnt[tid] = 0;
    }
    __syncthreads();
    for (int o = 1; o < NB2; o <<= 1) {
        int t = (tid < NB2 && tid >= o) ? sg[tid - o] : 0;
        __syncthreads();
        if (tid < NB2) sg[tid] += t;
        __syncthreads();
    }
    int e0 = blockIdx.x * (1024 * PEPT);
    unsigned myP[PEPT];
    int myB[PEPT], myR[PEPT];
#pragma unroll
    for (int j = 0; j < PEPT; ++j) {
        int e = e0 + j * 1024 + tid;
        if (e < E) {
            int d = dst[e];
            int s = src[e];
            int b = (unsigned)d / (unsigned)npb;
            myB[j] = b;
            myR[j] = atomicAdd(&cnt[b], 1);
            myP[j] = ((unsigned)(d - b * npb) << 23) | (unsigned)s;
        } else {
            myB[j] = -1;
        }
    }
    __syncthreads();
    if (tid < nb && cnt[tid] > 0)
        base_s[tid] = (sg[tid] - gcnt[tid]) + atomicAdd(&cur2[tid], cnt[tid]);
    __syncthreads();
#pragma unroll
    for (int j = 0; j < PEPT; ++j) {
        if (myB[j] >= 0) packed[base_s[myB[j]] + myR[j]] = myP[j];
    }
}

__global__ __launch_bounds__(1024, 2) void csr_gather2_kernel(
        const unsigned* __restrict__ packed, const int* __restrict__ gcnt,
        const unsigned short* __restrict__ featb,
        int* __restrict__ csr_g, unsigned short* __restrict__ rstb,
        int n, int npb, int nb) {
    __shared__ int sg[NB2];
    __shared__ int hist[NPB2];
    __shared__ int start[NPB2];
    __shared__ int cursor[NPB2];
    __shared__ unsigned raw[CAP2];
    __shared__ int srt[CAP2];

    int b = blockIdx.x;
    int tid = threadIdx.x;
    int node0 = b * npb;

    if (tid < NB2) sg[tid] = (tid < nb) ? gcnt[tid] : 0;
    if (tid < NPB2) hist[tid] = 0;
    __syncthreads();
    for (int o = 1; o < NB2; o <<= 1) {
        int t = (tid < NB2 && tid >= o) ? sg[tid - o] : 0;
        __syncthreads();
        if (tid < NB2) sg[tid] += t;
        __syncthreads();
    }
    int ie = sg[b];
    int ib = (b > 0) ? sg[b - 1] : 0;
    bool useG = (ie - ib) > CAP2;

    for (int k = ib + tid; k < ie; k += 1024) {
        unsigned p = packed[k];
        if (!useG) raw[k - ib] = p;
        atomicAdd(&hist[p >> 23], 1);
    }
    __syncthreads();

    if (tid < NPB2) start[tid] = hist[tid];
    __syncthreads();
    for (int o = 1; o < NPB2; o <<= 1) {
        int t = (tid < NPB2 && tid >= o) ? start[tid - o] : 0;
        __syncthreads();
        if (tid < NPB2) start[tid] += t;
        __syncthreads();
    }
    if (tid < NPB2) {
        int excl = start[tid] - hist[tid];
        start[tid] = excl;
        cursor[tid] = excl;
    }
    __syncthreads();

    int cnt_e = ie - ib;
    if (!useG) {
        for (int k = tid; k < cnt_e; k += 1024) {
            unsigned p = raw[k];
            int pos = atomicAdd(&cursor[p >> 23], 1);
            srt[pos] = (int)(p & SRC_MASK);
        }
    } else {
        for (int k = ib + tid; k < ie; k += 1024) {
            unsigned p = packed[k];
            int pos = atomicAdd(&cursor[p >> 23], 1);
            csr_g[ib + pos] = (int)(p & SRC_MASK);
        }
    }
    __syncthreads();

    int g = tid & 7;
    const bf16x8* f8 = reinterpret_cast<const bf16x8*>(featb);
    for (int ln = tid >> 3; ln < npb; ln += 128) {
        int node = node0 + ln;
        if (node >= n) break;
        bf16x8 self = f8[node * 8 + g];
        float acc[8];
#pragma unroll
        for (int j = 0; j < 8; ++j) acc[j] = (float)self[j];

        int s0 = start[ln];
        int e1 = s0 + hist[ln];
        const int* lst = useG ? (csr_g + ib) : srt;
        int i = s0;
        for (; i + 4 <= e1; i += 4) {
            int u0 = lst[i + 0];
            int u1 = lst[i + 1];
            int u2 = lst[i + 2];
            int u3 = lst[i + 3];
            bf16x8 v0 = f8[u0 * 8 + g];
            bf16x8 v1 = f8[u1 * 8 + g];
            bf16x8 v2 = f8[u2 * 8 + g];
            bf16x8 v3 = f8[u3 * 8 + g];
#pragma unroll
            for (int j = 0; j < 8; ++j)
                acc[j] += ((float)v0[j] + (float)v1[j]) +
                          ((float)v2[j] + (float)v3[j]);
        }
        for (; i < e1; ++i) {
            bf16x8 v = f8[lst[i] * 8 + g];
#pragma unroll
            for (int j = 0; j < 8; ++j) acc[j] += (float)v[j];
        }

        uint4v o = { pack_bf16x2(acc[0], acc[1]), pack_bf16x2(acc[2], acc[3]),
                     pack_bf16x2(acc[4], acc[5]), pack_bf16x2(acc[6], acc[7]) };
        reinterpret_cast<uint4v*>(rstb)[node * 8 + g] = o;
    }
}

// ===========================================================================
// Fused MFMA MLP: out^T = W2^T @ relu(W1^T @ rst^T + b1) + b2
// (round-9-proven form: 1 tile/wave, 391 blocks)
// ===========================================================================
template <bool BF16>
__global__ __launch_bounds__(512, 4) void mlp_mfma_kernel(
        const void* __restrict__ rstv, const bf16x8* __restrict__ wf,
        const float* __restrict__ b1, const float* __restrict__ b2,
        float* __restrict__ out, int n, int ntiles) {
    __shared__ bf16x8 swf[64 * 64];   // 64 KiB
    __shared__ float sb1[H];
    __shared__ float sb2[D];

    for (int i = threadIdx.x; i < 64 * 64; i += 512) swf[i] = wf[i];
    if (threadIdx.x < H) sb1[threadIdx.x] = b1[threadIdx.x];
    if (threadIdx.x < D) sb2[threadIdx.x] = b2[threadIdx.x];
    __syncthreads();

    int lane = threadIdx.x & 63;
    int wid  = threadIdx.x >> 6;
    int g = lane >> 5, c = lane & 31;

    int tile = blockIdx.x * 8 + wid;
    if (tile >= ntiles) return;
    int node = tile * 32 + c;
    bool valid = node < n;
    int nodeC = valid ? node : (n - 1);

    bf16x8 bfr[4];
    if constexpr (BF16) {
        const bf16x8* rb = reinterpret_cast<const bf16x8*>(rstv) +
                           (size_t)nodeC * 8 + g;
#pragma unroll
        for (int ks = 0; ks < 4; ++ks) bfr[ks] = rb[2 * ks];
    } else {
        const float* rrow = reinterpret_cast<const float*>(rstv) +
                            (size_t)nodeC * D + 8 * g;
#pragma unroll
        for (int ks = 0; ks < 4; ++ks) {
            float4 lo = *reinterpret_cast<const float4*>(rrow + 16 * ks);
            float4 hi = *reinterpret_cast<const float4*>(rrow + 16 * ks + 4);
            bf16x8 v;
            v[0] = (__bf16)lo.x; v[1] = (__bf16)lo.y; v[2] = (__bf16)lo.z; v[3] = (__bf16)lo.w;
            v[4] = (__bf16)hi.x; v[5] = (__bf16)hi.y; v[6] = (__bf16)hi.z; v[7] = (__bf16)hi.w;
            bfr[ks] = v;
        }
    }

    f32x16 acc2_0 = {};
    f32x16 acc2_1 = {};

#pragma unroll
    for (int ht = 0; ht < 8; ++ht) {
        f32x16 a1 = {};
#pragma unroll
        for (int ks = 0; ks < 4; ++ks)
            a1 = __builtin_amdgcn_mfma_f32_32x32x16_bf16(
                     swf[(ht * 4 + ks) * 64 + lane], bfr[ks], a1, 0, 0, 0);

        float hv[16];
#pragma unroll
        for (int q = 0; q < 4; ++q) {
            float4 bq = *reinterpret_cast<const float4*>(&sb1[32 * ht + 8 * q + 4 * g]);
            hv[4 * q + 0] = fmaxf(a1[4 * q + 0] + bq.x, 0.0f);
            hv[4 * q + 1] = fmaxf(a1[4 * q + 1] + bq.y, 0.0f);
            hv[4 * q + 2] = fmaxf(a1[4 * q + 2] + bq.z, 0.0f);
            hv[4 * q + 3] = fmaxf(a1[4 * q + 3] + bq.w, 0.0f);
        }

#pragma unroll
        for (int half = 0; half < 2; ++half) {
            const float* hs = hv + 8 * half;
            unsigned plo0 = pack_bf16x2(hs[0], hs[1]);
            unsigned plo1 = pack_bf16x2(hs[2], hs[3]);
            unsigned phi0 = pack_bf16x2(hs[4], hs[5]);
            unsigned phi1 = pack_bf16x2(hs[6], hs[7]);
            unsigned f0, f2, f1, f3;
            lane32_swap(plo0, phi0, f0, f2);
            lane32_swap(plo1, phi1, f1, f3);
            uint4v fr = { f0, f1, f2, f3 };
            bf16x8 b2f = __builtin_bit_cast(bf16x8, fr);
            int ks2 = 2 * ht + half;
            acc2_0 = __builtin_amdgcn_mfma_f32_32x32x16_bf16(
                         swf[(32 + 0 * 16 + ks2) * 64 + lane], b2f, acc2_0, 0, 0, 0);
            acc2_1 = __builtin_amdgcn_mfma_f32_32x32x16_bf16(
                         swf[(32 + 1 * 16 + ks2) * 64 + lane], b2f, acc2_1, 0, 0, 0);
        }
    }

    if (!valid) return;
    float* orow = out + (size_t)node * D;
#pragma unroll
    for (int dt = 0; dt < 2; ++dt) {
        const f32x16& a = dt ? acc2_1 : acc2_0;
#pragma unroll
        for (int q = 0; q < 4; ++q) {
            int d0 = 32 * dt + 8 * q + 4 * g;
            float4 bq = *reinterpret_cast<const float4*>(&sb2[d0]);
            float4 v;
            v.x = a[4 * q + 0] + bq.x;
            v.y = a[4 * q + 1] + bq.y;
            v.z = a[4 * q + 2] + bq.z;
            v.w = a[4 * q + 3] + bq.w;
            *reinterpret_cast<float4*>(orow + d0) = v;
        }
    }
}

// ===========================================================================
// TIER 3 — atomic fallback
// ===========================================================================
__global__ void copy_feat_kernel(const float* __restrict__ feat,
                                 float* __restrict__ rst, int n4) {
    int i = blockIdx.x * blockDim.x + threadIdx.x;
    if (i < n4) {
        reinterpret_cast<float4*>(rst)[i] =
            reinterpret_cast<const float4*>(feat)[i];
    }
}

__global__ void scatter_add_kernel(const float* __restrict__ feat,
                                   const int* __restrict__ src,
                                   const int* __restrict__ dst,
                                   float* rst, int E) {
    int gid = blockIdx.x * blockDim.x + threadIdx.x;
    int e = gid >> 4;
    if (e >= E) return;
    int d4 = (gid & 15) << 2;
    int s = src[e];
    int t = dst[e];
    float4 v = *reinterpret_cast<const float4*>(&feat[s * D + d4]);
    float* p = &rst[t * D + d4];
    atomicAdd(p + 0, v.x);
    atomicAdd(p + 1, v.y);
    atomicAdd(p + 2, v.z);
    atomicAdd(p + 3, v.w);
}

__global__ __launch_bounds__(512) void mlp_valu_kernel(
        const float* rst,
        const float* __restrict__ W1, const float* __restrict__ b1,
        const float* __restrict__ W2, const float* __restrict__ b2,
        float* out, int n) {
    __shared__ float sW1t[H * D];
    __shared__ float sW2 [H * D];
    __shared__ float sb1[H];
    __shared__ float sb2[D];

    for (int i = threadIdx.x; i < D * H; i += 512) {
        int d = i >> 8;
        int j = i & (H - 1);
        sW1t[j * D + d] = W1[i];
        sW2[i] = W2[i];
    }
    if (threadIdx.x < H) sb1[threadIdx.x] = b1[threadIdx.x];
    if (threadIdx.x < D) sb2[threadIdx.x] = b2[threadIdx.x];
    __syncthreads();

    int node = blockIdx.x * 512 + threadIdx.x;
    if (node >= n) return;

    float x[D];
    const float4* xr = reinterpret_cast<const float4*>(&rst[node * D]);
#pragma unroll
    for (int d4 = 0; d4 < D / 4; ++d4) {
        float4 v = xr[d4];
        x[d4 * 4 + 0] = v.x; x[d4 * 4 + 1] = v.y;
        x[d4 * 4 + 2] = v.z; x[d4 * 4 + 3] = v.w;
    }
    float acc[D];
#pragma unroll
    for (int d = 0; d < D; ++d) acc[d] = sb2[d];
    for (int j = 0; j < H; ++j) {
        float h = sb1[j];
        const float4* w1 = reinterpret_cast<const float4*>(&sW1t[j * D]);
#pragma unroll
        for (int d4 = 0; d4 < D / 4; ++d4) {
            float4 w = w1[d4];
            h += x[d4 * 4 + 0] * w.x + x[d4 * 4 + 1] * w.y +
                 x[d4 * 4 + 2] * w.z + x[d4 * 4 + 3] * w.w;
        }
        h = fmaxf(h, 0.0f);
        const float4* w2 = reinterpret_cast<const float4*>(&sW2[j * D]);
#pragma unroll
        for (int d4 = 0; d4 < D / 4; ++d4) {
            float4 w = w2[d4];
            acc[d4 * 4 + 0] += h * w.x; acc[d4 * 4 + 1] += h * w.y;
            acc[d4 * 4 + 2] += h * w.z; acc[d4 * 4 + 3] += h * w.w;
        }
    }
    float4* op = reinterpret_cast<float4*>(&out[node * D]);
#pragma unroll
    for (int d4 = 0; d4 < D / 4; ++d4) {
        float4 v;
        v.x = acc[d4 * 4 + 0]; v.y = acc[d4 * 4 + 1];
        v.z = acc[d4 * 4 + 2]; v.w = acc[d4 * 4 + 3];
        op[d4] = v;
    }
}

// ===========================================================================
extern "C" void kernel_launch(void* const* d_in, const int* in_sizes, int n_in,
                              void* d_out, int out_size, void* d_ws, size_t ws_size,
                              hipStream_t stream) {
    const float* feat = (const float*)d_in[0];
    const float* W1   = (const float*)d_in[1];
    const float* b1   = (const float*)d_in[2];
    const float* W2   = (const float*)d_in[3];
    const float* b2   = (const float*)d_in[4];
    const int*   src  = (const int*)d_in[5];
    const int*   dst  = (const int*)d_in[6];
    float* buf = (float*)d_out;

    int n = in_sizes[0] / D;
    int E = in_sizes[5];
    char* ws = (char*)d_ws;

    // ---------- tier 1 layout ----------
    int npbF = (n + NBF - 1) / NBF;
    int nbF  = (n + npbF - 1) / npbF;
    size_t o1 = 0;
    auto a1 = [&](size_t bytes) { size_t c = o1; o1 = (o1 + bytes + 255) & ~(size_t)255; return c; };
    size_t t1_wf     = a1(64 * 64 * sizeof(bf16x8));
    size_t t1_ctrl   = a1((NBF + 1) * sizeof(int));
    size_t t1_packed = a1((size_t)NBF * CAPF * sizeof(unsigned));
    size_t t1_ovf    = a1((size_t)E * sizeof(uint2));
    size_t t1_featb  = a1((size_t)n * D * 2);
    size_t t1_rstb   = a1((size_t)n * D * 2);
    size_t need1 = o1;
    bool tier1 = (npbF <= NPBF) && (ws_size >= need1);

    if (tier1) {
        bf16x8*   wf     = (bf16x8*)(ws + t1_wf);
        int*      ctrl   = (int*)(ws + t1_ctrl);
        unsigned* packed = (unsigned*)(ws + t1_packed);
        uint2*    ovf    = (uint2*)(ws + t1_ovf);
        unsigned short* featb = (unsigned short*)(ws + t1_featb);
        unsigned short* rstb  = (unsigned short*)(ws + t1_rstb);

        hipMemsetAsync(ctrl, 0, (NBF + 1) * sizeof(int), stream);

        int n8v  = n * D / 8;
        int cvtB = (n8v + 1023) / 1024;
        int pB   = (E + 1024 * PJ - 1) / (1024 * PJ);
        int prepB = 4;
        fused_front_kernel<<<pB + prepB + cvtB, 1024, 0, stream>>>(
            feat, featb, n8v, W1, W2, wf, src, dst, ctrl, packed, ovf,
            E, npbF, pB, prepB);

        csr_gather_fixed_kernel<<<nbF, 1024, 0, stream>>>(
            packed, ctrl, ovf, featb, rstb, n, npbF);

        int ntiles = (n + 31) / 32;
        mlp_mfma_kernel<true><<<(ntiles + 7) / 8, 512, 0, stream>>>(
            rstb, wf, b1, b2, buf, n, ntiles);
        return;
    }

    // ---------- tier 2 layout (round-8 path) ----------
    int npb2 = (n + NB2 - 1) / NB2;
    int nb2  = (n + npb2 - 1) / npb2;
    size_t o2 = 0;
    auto a2 = [&](size_t bytes) { size_t c = o2; o2 = (o2 + bytes + 255) & ~(size_t)255; return c; };
    size_t t2_wf     = a2(64 * 64 * sizeof(bf16x8));
    size_t t2_gcnt   = a2(2 * NB2 * sizeof(int));
    size_t t2_packed = a2((size_t)E * sizeof(unsigned));
    size_t t2_csrg   = a2((size_t)E * sizeof(int));
    size_t t2_featb  = a2((size_t)n * D * 2);
    size_t t2_rstb   = a2((size_t)n * D * 2);
    size_t need2 = o2;
    bool haveWf = ws_size >= 64 * 64 * sizeof(bf16x8);
    bool tier2  = (npb2 <= NPB2) && (n < (1 << 23)) && (ws_size >= need2);

    if (tier2) {
        bf16x8*   wf     = (bf16x8*)(ws + t2_wf);
        int*      gcnt   = (int*)(ws + t2_gcnt);
        int*      cur2   = gcnt + NB2;
        unsigned* packed = (unsigned*)(ws + t2_packed);
        int*      csr_g  = (int*)(ws + t2_csrg);
        unsigned short* featb = (unsigned short*)(ws + t2_featb);
        unsigned short* rstb  = (unsigned short*)(ws + t2_rstb);

        prep_weights_kernel<<<65, 64, 0, stream>>>(W1, W2, wf, gcnt);

        int n8   = n * D / 8;
        int cvtB = (n8 + 255) / 256;
        cvt_hist_kernel<<<cvtB + 784, 256, 0, stream>>>(
            feat, featb, n8, dst, E, gcnt, npb2, nb2, cvtB);

        int pB2 = (E + 1024 * PEPT - 1) / (1024 * PEPT);
        partition2_kernel<<<pB2, 1024, 0, stream>>>(
            src, dst, gcnt, cur2, packed, E, npb2, nb2);

        csr_gather2_kernel<<<nb2, 1024, 0, stream>>>(
            packed, gcnt, featb, csr_g, rstb, n, npb2, nb2);

        int ntiles = (n + 31) / 32;
        mlp_mfma_kernel<true><<<(ntiles + 7) / 8, 512, 0, stream>>>(
            rstb, wf, b1, b2, buf, n, ntiles);
        return;
    }

    // ---------- tier 3: atomic fallback ----------
    if (haveWf) {
        bf16x8* wf = (bf16x8*)ws;
        prep_weights_kernel<<<64, 64, 0, stream>>>(W1, W2, wf, (int*)ws);
        int n4 = n * D / 4;
        copy_feat_kernel<<<(n4 + 255) / 256, 256, 0, stream>>>(feat, buf, n4);
        int threads = E * 16;
        scatter_add_kernel<<<(threads + 255) / 256, 256, 0, stream>>>(
            feat, src, dst, buf, E);
        int ntiles = (n + 31) / 32;
        mlp_mfma_kernel<false><<<(ntiles + 7) / 8, 512, 0, stream>>>(
            buf, wf, b1, b2, buf, n, ntiles);
    } else {
        int n4 = n * D / 4;
        copy_feat_kernel<<<(n4 + 255) / 256, 256, 0, stream>>>(feat, buf, n4);
        int threads = E * 16;
        scatter_add_kernel<<<(threads + 255) / 256, 256, 0, stream>>>(
            feat, src, dst, buf, E);
        mlp_valu_kernel<<<(n + 511) / 512, 512, 0, stream>>>(
            buf, W1, b1, W2, b2, buf, n);
    }
}